// Round 8
// baseline (778.405 us; speedup 1.0000x reference)
//
#include <hip/hip_runtime.h>
#include <cstdint>
#include <cstddef>

#define NN 50000
#define NE 800000
#define NG 256
#define NLAY 7
#define NBLK 782   // 64-row tiles (fused2)
#define NBLK1 1563 // 32-row tiles (fused1)
#define CAP 18432  // bins capacity per dst-range

typedef float f32x4 __attribute__((ext_vector_type(4)));
typedef __bf16 bf16x8 __attribute__((ext_vector_type(8)));
typedef _Float16 h16x8 __attribute__((ext_vector_type(8)));

__device__ __forceinline__ float4 ld4(const float* p) { return *(const float4*)p; }
__device__ __forceinline__ void addh8(float4& x, float4& y, h16x8 v) {
  x.x += (float)v[0]; x.y += (float)v[1]; x.z += (float)v[2]; x.w += (float)v[3];
  y.x += (float)v[4]; y.y += (float)v[5]; y.z += (float)v[6]; y.w += (float)v[7];
}

// ---------------- init: zeros + hb=fp16(x) + W1/W2 -> MFMA-fragment order --------
// wf layout: pos = ((kc*16 + slot)*64 + lane)*8 + j, slot = (half*4+ct)*2 + hl.
__global__ void k_init(const float* __restrict__ x, const float* __restrict__ W1,
                       const float* __restrict__ W2, int* __restrict__ counts,
                       int* __restrict__ gcur, float* __restrict__ pooled,
                       _Float16* __restrict__ hb,
                       __bf16* __restrict__ w1f, __bf16* __restrict__ w2f,
                       float* __restrict__ psums) {
  int i = blockIdx.x * 256 + threadIdx.x;  // grid 25000 -> 6.4M
  if (i < NN) counts[i] = 0;
  if (i < 49) gcur[i] = i * CAP;
  if (i < NLAY * 256) psums[i] = 0.f;      // per-layer BN atomic accumulators
  if (i < NG * 1792) pooled[i] = 0.f;
  if (i < NN * 128) hb[i] = (_Float16)x[i];
  if (i < NLAY * 32768) {
    int l = i >> 15, pos = i & 32767;
    int j = pos & 7, ln = (pos >> 3) & 63, slot = (pos >> 9) & 15, kc = pos >> 13;
    int hl = slot & 1, ctp = (slot >> 1) & 3, hfp = slot >> 3;
    int n = hfp * 64 + ctp * 16 + (ln & 15);
    int k = kc * 32 + ((ln >> 4) << 3) + j;
    float a = W1[l * 16384 + k * 128 + n];
    float b = W2[l * 16384 + k * 128 + n];
    __bf16 ah = (__bf16)a, bh = (__bf16)b;
    w1f[i] = hl ? (__bf16)(a - (float)ah) : ah;
    w2f[i] = hl ? (__bf16)(b - (float)bh) : bh;
  }
}

__global__ void k_hist(const int* __restrict__ edge, int* __restrict__ counts) {
  int e = blockIdx.x * 256 + threadIdx.x;
  if (e < NE) atomicAdd(&counts[edge[NE + e]], 1);
}

// ---------------- parallel CSR scan ----------------
__global__ void k_part(const int* __restrict__ counts, int* __restrict__ bsum) {
  __shared__ int sm[256];
  int b = blockIdx.x, t = threadIdx.x;
  int i = b * 256 + t;
  sm[t] = (i < NN) ? counts[i] : 0;
  __syncthreads();
  for (int s = 128; s > 0; s >>= 1) {
    if (t < s) sm[t] += sm[t + s];
    __syncthreads();
  }
  if (t == 0) bsum[b] = sm[0];
}

__global__ void k_bscan(const int* __restrict__ bsum, int* __restrict__ boff,
                        int* __restrict__ row_ptr) {
  __shared__ int sm[256];
  int t = threadIdx.x;
  int v = (t < 196) ? bsum[t] : 0;
  sm[t] = v;
  __syncthreads();
  int val = v;
  for (int off = 1; off < 256; off <<= 1) {
    int o = (t >= off) ? sm[t - off] : 0;
    __syncthreads();
    val += o;
    sm[t] = val;
    __syncthreads();
  }
  if (t < 196) boff[t] = val - v;  // exclusive
  if (t == 255) row_ptr[NN] = val; // total = NE
}

__global__ void k_rowptr(const int* __restrict__ counts, const int* __restrict__ boff,
                         int* __restrict__ row_ptr) {
  __shared__ int sm[256];
  int b = blockIdx.x, t = threadIdx.x;
  int i = b * 256 + t;
  int c = (i < NN) ? counts[i] : 0;
  sm[t] = c;
  __syncthreads();
  int val = c;
  for (int off = 1; off < 256; off <<= 1) {
    int o = (t >= off) ? sm[t - off] : 0;
    __syncthreads();
    val += o;
    sm[t] = val;
    __syncthreads();
  }
  if (i < NN) row_ptr[i] = val - c + boff[b];
}

// ---------------- binned CSR build ----------------
__global__ __launch_bounds__(256) void k_binA(const int* __restrict__ edge,
                                              int* __restrict__ gcur,
                                              unsigned int* __restrict__ bins) {
  __shared__ int lh[49], lbase[49], lt[49];
  const int tid = threadIdx.x;
  const int e0 = blockIdx.x * 3125, e1 = e0 + 3125;
  if (tid < 49) { lh[tid] = 0; lt[tid] = 0; }
  __syncthreads();
  for (int e = e0 + tid; e < e1; e += 256)
    atomicAdd(&lh[edge[NE + e] >> 10], 1);
  __syncthreads();
  if (tid < 49) lbase[tid] = atomicAdd(&gcur[tid], lh[tid]);
  __syncthreads();
  for (int e = e0 + tid; e < e1; e += 256) {
    int dst = edge[NE + e], src = edge[e];
    int r = dst >> 10;
    int t = atomicAdd(&lt[r], 1);
    bins[lbase[r] + t] = ((unsigned)dst << 16) | (unsigned)src;
  }
}

__global__ __launch_bounds__(512) void k_binB(const int* __restrict__ row_ptr,
                                              const int* __restrict__ gcur,
                                              const unsigned int* __restrict__ bins,
                                              unsigned short* __restrict__ csr16) {
  __shared__ int lcur[1024];
  __shared__ unsigned short lcsr[24576];  // 48 KB
  const int blk = blockIdx.x, tid = threadIdx.x;
  const int base = blk << 10;
  const int nn = (base + 1024 <= NN) ? 1024 : (NN - base);
  const int seg0 = row_ptr[base];
  const int seg1 = row_ptr[(base + 1024 <= NN) ? (base + 1024) : NN];
  for (int i = tid; i < nn; i += 512) lcur[i] = row_ptr[base + i] - seg0;
  __syncthreads();
  const int tot = gcur[blk] - blk * CAP;
  for (int t = tid; t < tot; t += 512) {
    unsigned int p = bins[blk * CAP + t];
    int dst = (int)(p >> 16), src = (int)(p & 0xffffu);
    int pos = atomicAdd(&lcur[dst - base], 1);
    lcsr[pos] = (unsigned short)src;
  }
  __syncthreads();
  for (int i = tid; i < seg1 - seg0; i += 512) csr16[seg0 + i] = lcsr[i];
}

// ---------------- split fp32x8 -> bf16 hi/lo fragments ----------------
__device__ __forceinline__ void split8(const float4 v0, const float4 v1,
                                       bf16x8& hi, bf16x8& lo) {
  float f[8] = {v0.x, v0.y, v0.z, v0.w, v1.x, v1.y, v1.z, v1.w};
  #pragma unroll
  for (int j = 0; j < 8; ++j) {
    __bf16 h = (__bf16)f[j];
    hi[j] = h;
    lo[j] = (__bf16)(f[j] - (float)h);
  }
}

// ---------------- MFMA phase (M=64, 8 waves, acc[4]) for fused2 ----------------
__device__ __forceinline__ void mfma_phase(
    int tid, const __bf16* __restrict__ wf, float (*zs)[132], f32x4 acc[4])
{
  const int wv = tid >> 6, stripe = wv >> 1, half = wv & 1;
  const int lane = tid & 63, q = lane >> 4, m = lane & 15;
  #pragma unroll
  for (int kc = 0; kc < 4; ++kc) {
    const int k0 = kc * 32 + q * 8;
    float4 v0 = *(const float4*)&zs[stripe * 16 + m][k0];
    float4 v1 = *(const float4*)&zs[stripe * 16 + m][k0 + 4];
    bf16x8 ah, al;
    split8(v0, v1, ah, al);
    #pragma unroll
    for (int ct = 0; ct < 4; ++ct) {
      const int sbase = (half * 4 + ct) * 2;
      const __bf16* bp = wf + (((size_t)(kc * 16 + sbase) * 64 + lane) << 3);
      bf16x8 bh = *(const bf16x8*)bp;
      bf16x8 bl = *(const bf16x8*)(bp + 512);  // slot+1 = +64 lanes * 8
      acc[ct] = __builtin_amdgcn_mfma_f32_16x16x32_bf16(ah, bh, acc[ct], 0, 0, 0);
      acc[ct] = __builtin_amdgcn_mfma_f32_16x16x32_bf16(ah, bl, acc[ct], 0, 0, 0);
      acc[ct] = __builtin_amdgcn_mfma_f32_16x16x32_bf16(al, bh, acc[ct], 0, 0, 0);
    }
  }
  __syncthreads();  // zs dead after; callers reuse as scratch
}

// ---------------- FUSED1 v3: 32-row tile, 8-edge ILP + 4/2/1 tail cascade -------
// R6 post-mortem: gather ~5 TB/s logical (near L3 service rate); remaining serial
// cost is the tail (mean 3.5 edges, 1 dependent load each). Cascade cuts serial
// rounds to <=3 (mean ~1.75). BN partials now atomicAdd'd to per-layer psums
// (stream-ordered; replaces k_bnfin launch).
__global__ __launch_bounds__(512, 8) void k_fused1(
    const _Float16* __restrict__ hb, const int* __restrict__ row_ptr,
    const unsigned short* __restrict__ csr_src, const __bf16* __restrict__ wf,
    const float* __restrict__ bias, _Float16* __restrict__ zb,
    float* __restrict__ ps)   // ps = psums + layer*256: [0:128)=sum, [128:256)=sumsq
{
  __shared__ float zs[32][132];
  const int tid = threadIdx.x;
  const int m0 = blockIdx.x * 32;

  // ---- phase 1: gather agg = h[r] + sum h[src] ----
  {
    const int lr = tid >> 4;     // 0..31 rows
    const int sub = tid & 15;    // 8 cols each
    const int r = m0 + lr;
    const int c0 = sub << 3;
    float4 a0 = make_float4(0.f, 0.f, 0.f, 0.f), a1 = a0;
    if (r < NN) {
      addh8(a0, a1, *(const h16x8*)(hb + ((size_t)r << 7) + c0));
      int e = row_ptr[r], e1 = row_ptr[r + 1];
      for (; e + 7 < e1; e += 8) {
        const h16x8 v0 = *(const h16x8*)(hb + ((size_t)csr_src[e + 0] << 7) + c0);
        const h16x8 v1 = *(const h16x8*)(hb + ((size_t)csr_src[e + 1] << 7) + c0);
        const h16x8 v2 = *(const h16x8*)(hb + ((size_t)csr_src[e + 2] << 7) + c0);
        const h16x8 v3 = *(const h16x8*)(hb + ((size_t)csr_src[e + 3] << 7) + c0);
        const h16x8 v4 = *(const h16x8*)(hb + ((size_t)csr_src[e + 4] << 7) + c0);
        const h16x8 v5 = *(const h16x8*)(hb + ((size_t)csr_src[e + 5] << 7) + c0);
        const h16x8 v6 = *(const h16x8*)(hb + ((size_t)csr_src[e + 6] << 7) + c0);
        const h16x8 v7 = *(const h16x8*)(hb + ((size_t)csr_src[e + 7] << 7) + c0);
        // fp16 pairwise tree (3 deep, values O(1): err ~1e-2 abs per group)
        h16x8 t0 = v0 + v1, t1 = v2 + v3, t2 = v4 + v5, t3 = v6 + v7;
        h16x8 u0 = t0 + t1, u1 = t2 + t3;
        addh8(a0, a1, u0 + u1);
      }
      if (e + 3 < e1) {
        const h16x8 v0 = *(const h16x8*)(hb + ((size_t)csr_src[e + 0] << 7) + c0);
        const h16x8 v1 = *(const h16x8*)(hb + ((size_t)csr_src[e + 1] << 7) + c0);
        const h16x8 v2 = *(const h16x8*)(hb + ((size_t)csr_src[e + 2] << 7) + c0);
        const h16x8 v3 = *(const h16x8*)(hb + ((size_t)csr_src[e + 3] << 7) + c0);
        h16x8 t0 = v0 + v1, t1 = v2 + v3;
        addh8(a0, a1, t0 + t1);
        e += 4;
      }
      if (e + 1 < e1) {
        const h16x8 v0 = *(const h16x8*)(hb + ((size_t)csr_src[e + 0] << 7) + c0);
        const h16x8 v1 = *(const h16x8*)(hb + ((size_t)csr_src[e + 1] << 7) + c0);
        addh8(a0, a1, v0 + v1);
        e += 2;
      }
      if (e < e1)
        addh8(a0, a1, *(const h16x8*)(hb + ((size_t)csr_src[e] << 7) + c0));
    }
    *(float4*)&zs[lr][c0 + 0] = a0;
    *(float4*)&zs[lr][c0 + 4] = a1;
  }
  __syncthreads();

  // ---- phase 2: MFMA, M=32: 8 waves = 2 stripes x 2 halves x 2 ct-pairs ----
  const int wv = tid >> 6;
  const int stripe = wv >> 2, half = (wv >> 1) & 1, cpair = wv & 1;
  const int lane = tid & 63, q = lane >> 4, m = lane & 15;
  f32x4 acc[2] = {};
  #pragma unroll
  for (int kc = 0; kc < 4; ++kc) {
    const int k0 = kc * 32 + q * 8;
    float4 v0 = *(const float4*)&zs[stripe * 16 + m][k0];
    float4 v1 = *(const float4*)&zs[stripe * 16 + m][k0 + 4];
    bf16x8 ah, al;
    split8(v0, v1, ah, al);
    #pragma unroll
    for (int j = 0; j < 2; ++j) {
      const int ct = cpair * 2 + j;
      const int sbase = (half * 4 + ct) * 2;
      const __bf16* bp = wf + (((size_t)(kc * 16 + sbase) * 64 + lane) << 3);
      bf16x8 bh = *(const bf16x8*)bp;
      bf16x8 bl = *(const bf16x8*)(bp + 512);
      acc[j] = __builtin_amdgcn_mfma_f32_16x16x32_bf16(ah, bh, acc[j], 0, 0, 0);
      acc[j] = __builtin_amdgcn_mfma_f32_16x16x32_bf16(ah, bl, acc[j], 0, 0, 0);
      acc[j] = __builtin_amdgcn_mfma_f32_16x16x32_bf16(al, bh, acc[j], 0, 0, 0);
    }
  }
  __syncthreads();  // zs dead; reuse as reduction scratch

  // ---- epilogue: bias, fp16 z1 store, BN partials (8 slots/col) ----
  float* red_s = (float*)zs;          // 128*9
  float* red_q = red_s + 1152;        // 128*9
  const int sl = stripe * 4 + q;      // 0..7
  #pragma unroll
  for (int j = 0; j < 2; ++j) {
    const int ct = cpair * 2 + j;
    const int col = half * 64 + ct * 16 + m;
    const float bb = bias[col];
    float s = 0.f, qq = 0.f;
    #pragma unroll
    for (int i = 0; i < 4; ++i) {
      int r = m0 + stripe * 16 + q * 4 + i;
      if (r < NN) {
        float o = acc[j][i] + bb;
        zb[((size_t)r << 7) + col] = (_Float16)o;
        s += o; qq += o * o;
      }
    }
    red_s[col * 9 + sl] = s;
    red_q[col * 9 + sl] = qq;
  }
  __syncthreads();
  if (tid < 128) {
    float s = 0.f, qq = 0.f;
    #pragma unroll
    for (int k = 0; k < 8; ++k) {
      s += red_s[tid * 9 + k];
      qq += red_q[tid * 9 + k];
    }
    atomicAdd(&ps[tid], s);
    atomicAdd(&ps[128 + tid], qq);
  }
}

// ---------------- FUSED2: BN-finalize (per-block) + affine+relu -> MFMA -> pool --
__global__ __launch_bounds__(512) void k_fused2(
    const _Float16* __restrict__ zb, const float* __restrict__ ps,
    const float* __restrict__ gamma, const float* __restrict__ beta,
    const __bf16* __restrict__ wf, const float* __restrict__ bias,
    _Float16* __restrict__ hb, const int* __restrict__ batch,
    float* __restrict__ pooled, int layer)
{
  __shared__ float zs[64][132];
  __shared__ float sab[256];
  const int tid = threadIdx.x;
  const int m0 = blockIdx.x * 64;

  // ---- phase 0: BN finalize from per-layer atomic sums (1 KB, L2-resident) ----
  if (tid < 128) {
    float s = ps[tid], q = ps[128 + tid];
    float mean = s * (1.f / NN);
    float var = q * (1.f / NN) - mean * mean;
    float rstd = rsqrtf(var + 1e-5f);
    float a = gamma[tid] * rstd;
    sab[tid] = a;
    sab[128 + tid] = beta[tid] - mean * a;
  }
  __syncthreads();

  // ---- phase 1: coalesced fp16 load + vector affine + relu -> zs ----
  {
    const int lr = tid >> 3;     // 0..63
    const int sub = tid & 7;     // 16 cols
    const int r = m0 + lr;
    const int c0 = sub << 4;
    h16x8 u0 = {}, u1 = {};
    if (r < NN) {
      const _Float16* rp = zb + ((size_t)r << 7) + c0;
      u0 = *(const h16x8*)rp;
      u1 = *(const h16x8*)(rp + 8);
    }
    float4 v0 = make_float4((float)u0[0], (float)u0[1], (float)u0[2], (float)u0[3]);
    float4 v1 = make_float4((float)u0[4], (float)u0[5], (float)u0[6], (float)u0[7]);
    float4 v2 = make_float4((float)u1[0], (float)u1[1], (float)u1[2], (float)u1[3]);
    float4 v3 = make_float4((float)u1[4], (float)u1[5], (float)u1[6], (float)u1[7]);
    float4 s0 = *(float4*)&sab[c0], s1 = *(float4*)&sab[c0 + 4];
    float4 s2 = *(float4*)&sab[c0 + 8], s3 = *(float4*)&sab[c0 + 12];
    float4 o0 = *(float4*)&sab[128 + c0], o1 = *(float4*)&sab[128 + c0 + 4];
    float4 o2 = *(float4*)&sab[128 + c0 + 8], o3 = *(float4*)&sab[128 + c0 + 12];
    float4 y0, y1, y2, y3;
    y0.x = fmaxf(fmaf(s0.x, v0.x, o0.x), 0.f); y0.y = fmaxf(fmaf(s0.y, v0.y, o0.y), 0.f);
    y0.z = fmaxf(fmaf(s0.z, v0.z, o0.z), 0.f); y0.w = fmaxf(fmaf(s0.w, v0.w, o0.w), 0.f);
    y1.x = fmaxf(fmaf(s1.x, v1.x, o1.x), 0.f); y1.y = fmaxf(fmaf(s1.y, v1.y, o1.y), 0.f);
    y1.z = fmaxf(fmaf(s1.z, v1.z, o1.z), 0.f); y1.w = fmaxf(fmaf(s1.w, v1.w, o1.w), 0.f);
    y2.x = fmaxf(fmaf(s2.x, v2.x, o2.x), 0.f); y2.y = fmaxf(fmaf(s2.y, v2.y, o2.y), 0.f);
    y2.z = fmaxf(fmaf(s2.z, v2.z, o2.z), 0.f); y2.w = fmaxf(fmaf(s2.w, v2.w, o2.w), 0.f);
    y3.x = fmaxf(fmaf(s3.x, v3.x, o3.x), 0.f); y3.y = fmaxf(fmaf(s3.y, v3.y, o3.y), 0.f);
    y3.z = fmaxf(fmaf(s3.z, v3.z, o3.z), 0.f); y3.w = fmaxf(fmaf(s3.w, v3.w, o3.w), 0.f);
    *(float4*)&zs[lr][c0 + 0] = y0;
    *(float4*)&zs[lr][c0 + 4] = y1;
    *(float4*)&zs[lr][c0 + 8] = y2;
    *(float4*)&zs[lr][c0 + 12] = y3;
  }
  __syncthreads();

  // ---- phase 2: MFMA (barrier-free B) ----
  const int wv = tid >> 6, stripe = wv >> 1, half = wv & 1;
  const int lane = tid & 63, q = lane >> 4, m = lane & 15;
  f32x4 acc[4] = {};
  mfma_phase(tid, wf, zs, acc);

  // ---- epilogue: bias+relu, fp16 h store, pooling ----
  int bg[4];
  #pragma unroll
  for (int i = 0; i < 4; ++i) {
    int r = m0 + stripe * 16 + q * 4 + i;
    bg[i] = (r < NN) ? batch[r] : -1;
  }
  #pragma unroll
  for (int ct = 0; ct < 4; ++ct) {
    const int col = half * 64 + ct * 16 + m;
    const float bb = bias[col];
    #pragma unroll
    for (int i = 0; i < 4; ++i) {
      int r = m0 + stripe * 16 + q * 4 + i;
      float v = fmaxf(acc[ct][i] + bb, 0.f);
      acc[ct][i] = v;
      if (r < NN) hb[((size_t)r << 7) + col] = (_Float16)v;
    }
  }

  int gstart = batch[m0];
  int gend = batch[(m0 + 63 < NN) ? (m0 + 63) : (NN - 1)];
  float* red_s = (float*)zs;          // 128*17
  float* red_m = red_s + 2176;        // 128*17
  const int sl = stripe * 4 + q;
  for (int g = gstart; g <= gend; ++g) {
    __syncthreads();
    #pragma unroll
    for (int ct = 0; ct < 4; ++ct) {
      const int col = half * 64 + ct * 16 + m;
      float s = 0.f, mx = 0.f;
      #pragma unroll
      for (int i = 0; i < 4; ++i) {
        if (bg[i] == g) { s += acc[ct][i]; mx = fmaxf(mx, acc[ct][i]); }
      }
      red_s[col * 17 + sl] = s;
      red_m[col * 17 + sl] = mx;
    }
    __syncthreads();
    if (tid < 128) {
      float s = 0.f, mx = 0.f;
      #pragma unroll
      for (int k = 0; k < 16; ++k) {
        s += red_s[tid * 17 + k];
        mx = fmaxf(mx, red_m[tid * 17 + k]);
      }
      if (s != 0.f) atomicAdd(&pooled[g * 1792 + layer * 128 + tid], s);
      if (mx != 0.f)
        atomicMax((int*)&pooled[g * 1792 + 896 + layer * 128 + tid], __float_as_int(mx));
    }
  }
}

// ---------------- Wl1 prep: transpose + split via LDS tiles ----------------
__global__ __launch_bounds__(256) void k_wl1prep(
    const float* __restrict__ Wl1, __bf16* __restrict__ wh, __bf16* __restrict__ wl) {
  __shared__ float tile[32][33];
  const int k0 = blockIdx.x * 32, n0 = blockIdx.y * 32;
  const int lr = threadIdx.x >> 5, lc = threadIdx.x & 31;
  #pragma unroll
  for (int it = 0; it < 4; ++it) {
    int rr = lr + it * 8;
    tile[rr][lc] = Wl1[(size_t)(k0 + rr) * 1792 + n0 + lc];
  }
  __syncthreads();
  #pragma unroll
  for (int it = 0; it < 4; ++it) {
    int rr = lr + it * 8;
    float v = tile[lc][rr];
    __bf16 h = (__bf16)v;
    wh[(size_t)(n0 + rr) * 1792 + k0 + lc] = h;
    wl[(size_t)(n0 + rr) * 1792 + k0 + lc] = (__bf16)(v - (float)h);
  }
}

// ---------------- MLP1 (MFMA split-bf16, split-K=4): part = pooled @ Wl1 ----------
__global__ __launch_bounds__(256) void k_mlp1a(
    const float* __restrict__ P, const __bf16* __restrict__ wh,
    const __bf16* __restrict__ wl, float* __restrict__ part)
{
  const int tid = threadIdx.x;
  const int n0 = blockIdx.x * 64;
  const int m0 = blockIdx.y * 64;
  const int kc = blockIdx.z;          // 0..3, chunk of 448 k
  const int kbase = kc * 448;
  const int w = tid >> 6, lane = tid & 63, q = lane >> 4, m = lane & 15;
  const int row = m0 + w * 16 + m;    // < 256 always
  f32x4 acc[4] = {};
  const float* rp = P + (size_t)row * 1792;
  #pragma unroll 2
  for (int ks = 0; ks < 14; ++ks) {
    const int k0 = kbase + ks * 32 + q * 8;
    float4 v0 = ld4(rp + k0), v1 = ld4(rp + k0 + 4);
    bf16x8 ah, al;
    split8(v0, v1, ah, al);
    #pragma unroll
    for (int ct = 0; ct < 4; ++ct) {
      const int n = n0 + ct * 16 + m;
      bf16x8 bh = *(const bf16x8*)(wh + (size_t)n * 1792 + k0);
      bf16x8 bl = *(const bf16x8*)(wl + (size_t)n * 1792 + k0);
      acc[ct] = __builtin_amdgcn_mfma_f32_16x16x32_bf16(ah, bh, acc[ct], 0, 0, 0);
      acc[ct] = __builtin_amdgcn_mfma_f32_16x16x32_bf16(ah, bl, acc[ct], 0, 0, 0);
      acc[ct] = __builtin_amdgcn_mfma_f32_16x16x32_bf16(al, bh, acc[ct], 0, 0, 0);
    }
  }
  float* pp = part + (size_t)kc * 458752;
  #pragma unroll
  for (int ct = 0; ct < 4; ++ct) {
    const int n = n0 + ct * 16 + m;
    #pragma unroll
    for (int i = 0; i < 4; ++i) {
      int r = m0 + w * 16 + q * 4 + i;
      pp[(size_t)r * 1792 + n] = acc[ct][i];
    }
  }
}

// ---------------- MLP2 (merged: relu(part-sum + bl1) dot Wl2, per-group) ---------
__global__ void k_mlp2(const float* __restrict__ part, const float* __restrict__ bl1,
                       const float* __restrict__ Wl2, const float* __restrict__ bl2,
                       float* __restrict__ out) {
  __shared__ float red[256];
  int g = blockIdx.x, t = threadIdx.x;
  float p = 0.f;
  for (int k = t; k < 1792; k += 256) {
    size_t idx = (size_t)g * 1792 + k;
    float s = bl1[k];
    #pragma unroll
    for (int kc = 0; kc < 4; ++kc) s += part[(size_t)kc * 458752 + idx];
    p += fmaxf(s, 0.f) * Wl2[k];
  }
  red[t] = p;
  __syncthreads();
  for (int s = 128; s > 0; s >>= 1) {
    if (t < s) red[t] += red[t + s];
    __syncthreads();
  }
  if (t == 0) {
    float l = red[0] + bl2[0];
    out[g] = 1.f / (1.f + expf(-l));
    out[NG + g] = l;
  }
}

// ---------------- launch ----------------
extern "C" void kernel_launch(void* const* d_in, const int* in_sizes, int n_in,
                              void* d_out, int out_size, void* d_ws, size_t ws_size,
                              hipStream_t stream) {
  const float* x     = (const float*)d_in[0];
  const int*   edge  = (const int*)d_in[1];
  const int*   batch = (const int*)d_in[2];
  const float* W1    = (const float*)d_in[3];
  const float* b1    = (const float*)d_in[4];
  const float* gamma = (const float*)d_in[5];
  const float* beta  = (const float*)d_in[6];
  const float* W2    = (const float*)d_in[7];
  const float* b2    = (const float*)d_in[8];
  const float* Wl1   = (const float*)d_in[9];
  const float* bl1   = (const float*)d_in[10];
  const float* Wl2   = (const float*)d_in[11];
  const float* bl2   = (const float*)d_in[12];
  float* out = (float*)d_out;

  int* wsi = (int*)d_ws;
  int* row_ptr = wsi;                 // 50048
  int* counts  = wsi + 50048;         // 50048
  int* bsum    = wsi + 100096;        // 256
  int* boff    = wsi + 100352;        // 256
  int* gcur    = wsi + 100608;        // 64 (pad to 100864)
  unsigned short* csr16 = (unsigned short*)(wsi + 100864);  // 800000 u16
  float* wsf   = (float*)(wsi + 950912);
  // float-region layout:
  _Float16* zb     = (_Float16*)wsf;            // [50000,128] fp16 z1 (3.2M floats)
  _Float16* hb     = (_Float16*)(wsf + 6400000);// [50000,128] fp16 h (3.2M floats)
  float*    part   = wsf + 9600000;             // [4][256][1792] (MLP head only)
  float*    psums  = wsf + 12800000;            // [7][2][128] per-layer BN sums
  float*    pooled = wsf + 13000448;            // [256,1792] -> ends 13459200
  __bf16*   w1f    = (__bf16*)(wsf + 13459200); // 7*32768 bf16 frag-ordered
  __bf16*   w2f    = (__bf16*)(wsf + 13573888); // 7*32768 bf16 -> ends 13688576
  // bins aliases zb region (dead until first fused1; binB completes before layers)
  unsigned int* bins = (unsigned int*)wsf;      // 49*18432 u32 = 3.6 MB << zb size
  // post-layer aliases (zb region dead after last k_fused2):
  __bf16*   wl1h   = (__bf16*)wsf;              // 1792*1792 bf16
  __bf16*   wl1l   = (__bf16*)(wsf + 1605632);  // ends 3,211,264

  // prep: zeros + x->fp16 + frag-ordered W split; degree hist; CSR scan; binned fill
  k_init<<<25000, 256, 0, stream>>>(x, W1, W2, counts, gcur, pooled, hb, w1f, w2f,
                                    psums);
  k_hist<<<3125, 256, 0, stream>>>(edge, counts);
  k_part<<<196, 256, 0, stream>>>(counts, bsum);
  k_bscan<<<1, 256, 0, stream>>>(bsum, boff, row_ptr);
  k_rowptr<<<196, 256, 0, stream>>>(counts, boff, row_ptr);
  k_binA<<<256, 256, 0, stream>>>(edge, gcur, bins);
  k_binB<<<49, 512, 0, stream>>>(row_ptr, gcur, bins, csr16);

  for (int i = 0; i < NLAY; ++i) {
    k_fused1<<<NBLK1, 512, 0, stream>>>(hb, row_ptr, csr16, w1f + i * 32768,
                                        b1 + i * 128, zb, psums + i * 256);
    k_fused2<<<NBLK, 512, 0, stream>>>(zb, psums + i * 256, gamma + i * 128,
                                       beta + i * 128, w2f + i * 32768,
                                       b2 + i * 128, hb, batch, pooled, i);
  }
  // MLP head (zb region reused for Wl1 split)
  k_wl1prep<<<dim3(56, 56), 256, 0, stream>>>(Wl1, wl1h, wl1l);
  k_mlp1a<<<dim3(28, 4, 4), 256, 0, stream>>>(pooled, wl1h, wl1l, part);
  k_mlp2<<<256, 256, 0, stream>>>(part, bl1, Wl2, bl2, out);
}

// Round 9
// 625.462 us; speedup vs baseline: 1.2445x; 1.2445x over previous
//
#include <hip/hip_runtime.h>
#include <cstdint>
#include <cstddef>

#define NN 50000
#define NE 800000
#define NG 256
#define NLAY 7
#define NBLK 782   // 64-row tiles (fused2)
#define NBLK1 1563 // 32-row tiles (fused1)
#define NBUCK 16   // BN atomic buckets (contention 1563 -> ~98 per address)
#define CAP 18432  // bins capacity per dst-range

typedef float f32x4 __attribute__((ext_vector_type(4)));
typedef __bf16 bf16x8 __attribute__((ext_vector_type(8)));
typedef _Float16 h16x8 __attribute__((ext_vector_type(8)));

__device__ __forceinline__ float4 ld4(const float* p) { return *(const float4*)p; }
__device__ __forceinline__ void addh8(float4& x, float4& y, h16x8 v) {
  x.x += (float)v[0]; x.y += (float)v[1]; x.z += (float)v[2]; x.w += (float)v[3];
  y.x += (float)v[4]; y.y += (float)v[5]; y.z += (float)v[6]; y.w += (float)v[7];
}

// ---------------- init: zeros + hb=fp16(x) + W1/W2 -> MFMA-fragment order --------
// wf layout: pos = ((kc*16 + slot)*64 + lane)*8 + j, slot = (half*4+ct)*2 + hl.
__global__ void k_init(const float* __restrict__ x, const float* __restrict__ W1,
                       const float* __restrict__ W2, int* __restrict__ counts,
                       int* __restrict__ gcur, float* __restrict__ pooled,
                       _Float16* __restrict__ hb,
                       __bf16* __restrict__ w1f, __bf16* __restrict__ w2f,
                       float* __restrict__ psums) {
  int i = blockIdx.x * 256 + threadIdx.x;  // grid 25000 -> 6.4M
  if (i < NN) counts[i] = 0;
  if (i < 49) gcur[i] = i * CAP;
  if (i < NLAY * NBUCK * 256) psums[i] = 0.f;  // per-layer bucketed BN accumulators
  if (i < NG * 1792) pooled[i] = 0.f;
  if (i < NN * 128) hb[i] = (_Float16)x[i];
  if (i < NLAY * 32768) {
    int l = i >> 15, pos = i & 32767;
    int j = pos & 7, ln = (pos >> 3) & 63, slot = (pos >> 9) & 15, kc = pos >> 13;
    int hl = slot & 1, ctp = (slot >> 1) & 3, hfp = slot >> 3;
    int n = hfp * 64 + ctp * 16 + (ln & 15);
    int k = kc * 32 + ((ln >> 4) << 3) + j;
    float a = W1[l * 16384 + k * 128 + n];
    float b = W2[l * 16384 + k * 128 + n];
    __bf16 ah = (__bf16)a, bh = (__bf16)b;
    w1f[i] = hl ? (__bf16)(a - (float)ah) : ah;
    w2f[i] = hl ? (__bf16)(b - (float)bh) : bh;
  }
}

__global__ void k_hist(const int* __restrict__ edge, int* __restrict__ counts) {
  int e = blockIdx.x * 256 + threadIdx.x;
  if (e < NE) atomicAdd(&counts[edge[NE + e]], 1);
}

// ---------------- parallel CSR scan ----------------
__global__ void k_part(const int* __restrict__ counts, int* __restrict__ bsum) {
  __shared__ int sm[256];
  int b = blockIdx.x, t = threadIdx.x;
  int i = b * 256 + t;
  sm[t] = (i < NN) ? counts[i] : 0;
  __syncthreads();
  for (int s = 128; s > 0; s >>= 1) {
    if (t < s) sm[t] += sm[t + s];
    __syncthreads();
  }
  if (t == 0) bsum[b] = sm[0];
}

__global__ void k_bscan(const int* __restrict__ bsum, int* __restrict__ boff,
                        int* __restrict__ row_ptr) {
  __shared__ int sm[256];
  int t = threadIdx.x;
  int v = (t < 196) ? bsum[t] : 0;
  sm[t] = v;
  __syncthreads();
  int val = v;
  for (int off = 1; off < 256; off <<= 1) {
    int o = (t >= off) ? sm[t - off] : 0;
    __syncthreads();
    val += o;
    sm[t] = val;
    __syncthreads();
  }
  if (t < 196) boff[t] = val - v;  // exclusive
  if (t == 255) row_ptr[NN] = val; // total = NE
}

__global__ void k_rowptr(const int* __restrict__ counts, const int* __restrict__ boff,
                         int* __restrict__ row_ptr) {
  __shared__ int sm[256];
  int b = blockIdx.x, t = threadIdx.x;
  int i = b * 256 + t;
  int c = (i < NN) ? counts[i] : 0;
  sm[t] = c;
  __syncthreads();
  int val = c;
  for (int off = 1; off < 256; off <<= 1) {
    int o = (t >= off) ? sm[t - off] : 0;
    __syncthreads();
    val += o;
    sm[t] = val;
    __syncthreads();
  }
  if (i < NN) row_ptr[i] = val - c + boff[b];
}

// ---------------- binned CSR build ----------------
__global__ __launch_bounds__(256) void k_binA(const int* __restrict__ edge,
                                              int* __restrict__ gcur,
                                              unsigned int* __restrict__ bins) {
  __shared__ int lh[49], lbase[49], lt[49];
  const int tid = threadIdx.x;
  const int e0 = blockIdx.x * 3125, e1 = e0 + 3125;
  if (tid < 49) { lh[tid] = 0; lt[tid] = 0; }
  __syncthreads();
  for (int e = e0 + tid; e < e1; e += 256)
    atomicAdd(&lh[edge[NE + e] >> 10], 1);
  __syncthreads();
  if (tid < 49) lbase[tid] = atomicAdd(&gcur[tid], lh[tid]);
  __syncthreads();
  for (int e = e0 + tid; e < e1; e += 256) {
    int dst = edge[NE + e], src = edge[e];
    int r = dst >> 10;
    int t = atomicAdd(&lt[r], 1);
    bins[lbase[r] + t] = ((unsigned)dst << 16) | (unsigned)src;
  }
}

__global__ __launch_bounds__(512) void k_binB(const int* __restrict__ row_ptr,
                                              const int* __restrict__ gcur,
                                              const unsigned int* __restrict__ bins,
                                              unsigned short* __restrict__ csr16) {
  __shared__ int lcur[1024];
  __shared__ unsigned short lcsr[24576];  // 48 KB
  const int blk = blockIdx.x, tid = threadIdx.x;
  const int base = blk << 10;
  const int nn = (base + 1024 <= NN) ? 1024 : (NN - base);
  const int seg0 = row_ptr[base];
  const int seg1 = row_ptr[(base + 1024 <= NN) ? (base + 1024) : NN];
  for (int i = tid; i < nn; i += 512) lcur[i] = row_ptr[base + i] - seg0;
  __syncthreads();
  const int tot = gcur[blk] - blk * CAP;
  for (int t = tid; t < tot; t += 512) {
    unsigned int p = bins[blk * CAP + t];
    int dst = (int)(p >> 16), src = (int)(p & 0xffffu);
    int pos = atomicAdd(&lcur[dst - base], 1);
    lcsr[pos] = (unsigned short)src;
  }
  __syncthreads();
  for (int i = tid; i < seg1 - seg0; i += 512) csr16[seg0 + i] = lcsr[i];
}

// ---------------- split fp32x8 -> bf16 hi/lo fragments ----------------
__device__ __forceinline__ void split8(const float4 v0, const float4 v1,
                                       bf16x8& hi, bf16x8& lo) {
  float f[8] = {v0.x, v0.y, v0.z, v0.w, v1.x, v1.y, v1.z, v1.w};
  #pragma unroll
  for (int j = 0; j < 8; ++j) {
    __bf16 h = (__bf16)f[j];
    hi[j] = h;
    lo[j] = (__bf16)(f[j] - (float)h);
  }
}

// ---------------- MFMA phase (M=64, 8 waves, acc[4]) for fused2 ----------------
__device__ __forceinline__ void mfma_phase(
    int tid, const __bf16* __restrict__ wf, float (*zs)[132], f32x4 acc[4])
{
  const int wv = tid >> 6, stripe = wv >> 1, half = wv & 1;
  const int lane = tid & 63, q = lane >> 4, m = lane & 15;
  #pragma unroll
  for (int kc = 0; kc < 4; ++kc) {
    const int k0 = kc * 32 + q * 8;
    float4 v0 = *(const float4*)&zs[stripe * 16 + m][k0];
    float4 v1 = *(const float4*)&zs[stripe * 16 + m][k0 + 4];
    bf16x8 ah, al;
    split8(v0, v1, ah, al);
    #pragma unroll
    for (int ct = 0; ct < 4; ++ct) {
      const int sbase = (half * 4 + ct) * 2;
      const __bf16* bp = wf + (((size_t)(kc * 16 + sbase) * 64 + lane) << 3);
      bf16x8 bh = *(const bf16x8*)bp;
      bf16x8 bl = *(const bf16x8*)(bp + 512);  // slot+1 = +64 lanes * 8
      acc[ct] = __builtin_amdgcn_mfma_f32_16x16x32_bf16(ah, bh, acc[ct], 0, 0, 0);
      acc[ct] = __builtin_amdgcn_mfma_f32_16x16x32_bf16(ah, bl, acc[ct], 0, 0, 0);
      acc[ct] = __builtin_amdgcn_mfma_f32_16x16x32_bf16(al, bh, acc[ct], 0, 0, 0);
    }
  }
  __syncthreads();  // zs dead after; callers reuse as scratch
}

// ---------------- FUSED1 v4: 32-row tile, 8-edge ILP + 4/2/1 tail cascade -------
// R8 post-mortem: atomicAdd of all 1563 blocks onto ONE 256-float buffer cost
// +18us/launch (same-cache-line RMW serialization). v4: bucket the atomics 16x
// by blockIdx -> ~98 chains per address (sub-us). Everything else unchanged.
__global__ __launch_bounds__(512, 8) void k_fused1(
    const _Float16* __restrict__ hb, const int* __restrict__ row_ptr,
    const unsigned short* __restrict__ csr_src, const __bf16* __restrict__ wf,
    const float* __restrict__ bias, _Float16* __restrict__ zb,
    float* __restrict__ ps)   // ps = psums + layer*NBUCK*256; bucket b at ps+b*256
{
  __shared__ float zs[32][132];
  const int tid = threadIdx.x;
  const int m0 = blockIdx.x * 32;

  // ---- phase 1: gather agg = h[r] + sum h[src] ----
  {
    const int lr = tid >> 4;     // 0..31 rows
    const int sub = tid & 15;    // 8 cols each
    const int r = m0 + lr;
    const int c0 = sub << 3;
    float4 a0 = make_float4(0.f, 0.f, 0.f, 0.f), a1 = a0;
    if (r < NN) {
      addh8(a0, a1, *(const h16x8*)(hb + ((size_t)r << 7) + c0));
      int e = row_ptr[r], e1 = row_ptr[r + 1];
      for (; e + 7 < e1; e += 8) {
        const h16x8 v0 = *(const h16x8*)(hb + ((size_t)csr_src[e + 0] << 7) + c0);
        const h16x8 v1 = *(const h16x8*)(hb + ((size_t)csr_src[e + 1] << 7) + c0);
        const h16x8 v2 = *(const h16x8*)(hb + ((size_t)csr_src[e + 2] << 7) + c0);
        const h16x8 v3 = *(const h16x8*)(hb + ((size_t)csr_src[e + 3] << 7) + c0);
        const h16x8 v4 = *(const h16x8*)(hb + ((size_t)csr_src[e + 4] << 7) + c0);
        const h16x8 v5 = *(const h16x8*)(hb + ((size_t)csr_src[e + 5] << 7) + c0);
        const h16x8 v6 = *(const h16x8*)(hb + ((size_t)csr_src[e + 6] << 7) + c0);
        const h16x8 v7 = *(const h16x8*)(hb + ((size_t)csr_src[e + 7] << 7) + c0);
        // fp16 pairwise tree (3 deep, values O(1): err ~1e-2 abs per group)
        h16x8 t0 = v0 + v1, t1 = v2 + v3, t2 = v4 + v5, t3 = v6 + v7;
        h16x8 u0 = t0 + t1, u1 = t2 + t3;
        addh8(a0, a1, u0 + u1);
      }
      if (e + 3 < e1) {
        const h16x8 v0 = *(const h16x8*)(hb + ((size_t)csr_src[e + 0] << 7) + c0);
        const h16x8 v1 = *(const h16x8*)(hb + ((size_t)csr_src[e + 1] << 7) + c0);
        const h16x8 v2 = *(const h16x8*)(hb + ((size_t)csr_src[e + 2] << 7) + c0);
        const h16x8 v3 = *(const h16x8*)(hb + ((size_t)csr_src[e + 3] << 7) + c0);
        h16x8 t0 = v0 + v1, t1 = v2 + v3;
        addh8(a0, a1, t0 + t1);
        e += 4;
      }
      if (e + 1 < e1) {
        const h16x8 v0 = *(const h16x8*)(hb + ((size_t)csr_src[e + 0] << 7) + c0);
        const h16x8 v1 = *(const h16x8*)(hb + ((size_t)csr_src[e + 1] << 7) + c0);
        addh8(a0, a1, v0 + v1);
        e += 2;
      }
      if (e < e1)
        addh8(a0, a1, *(const h16x8*)(hb + ((size_t)csr_src[e] << 7) + c0));
    }
    *(float4*)&zs[lr][c0 + 0] = a0;
    *(float4*)&zs[lr][c0 + 4] = a1;
  }
  __syncthreads();

  // ---- phase 2: MFMA, M=32: 8 waves = 2 stripes x 2 halves x 2 ct-pairs ----
  const int wv = tid >> 6;
  const int stripe = wv >> 2, half = (wv >> 1) & 1, cpair = wv & 1;
  const int lane = tid & 63, q = lane >> 4, m = lane & 15;
  f32x4 acc[2] = {};
  #pragma unroll
  for (int kc = 0; kc < 4; ++kc) {
    const int k0 = kc * 32 + q * 8;
    float4 v0 = *(const float4*)&zs[stripe * 16 + m][k0];
    float4 v1 = *(const float4*)&zs[stripe * 16 + m][k0 + 4];
    bf16x8 ah, al;
    split8(v0, v1, ah, al);
    #pragma unroll
    for (int j = 0; j < 2; ++j) {
      const int ct = cpair * 2 + j;
      const int sbase = (half * 4 + ct) * 2;
      const __bf16* bp = wf + (((size_t)(kc * 16 + sbase) * 64 + lane) << 3);
      bf16x8 bh = *(const bf16x8*)bp;
      bf16x8 bl = *(const bf16x8*)(bp + 512);
      acc[j] = __builtin_amdgcn_mfma_f32_16x16x32_bf16(ah, bh, acc[j], 0, 0, 0);
      acc[j] = __builtin_amdgcn_mfma_f32_16x16x32_bf16(ah, bl, acc[j], 0, 0, 0);
      acc[j] = __builtin_amdgcn_mfma_f32_16x16x32_bf16(al, bh, acc[j], 0, 0, 0);
    }
  }
  __syncthreads();  // zs dead; reuse as reduction scratch

  // ---- epilogue: bias, fp16 z1 store, BN partials (8 slots/col) ----
  float* red_s = (float*)zs;          // 128*9
  float* red_q = red_s + 1152;        // 128*9
  const int sl = stripe * 4 + q;      // 0..7
  #pragma unroll
  for (int j = 0; j < 2; ++j) {
    const int ct = cpair * 2 + j;
    const int col = half * 64 + ct * 16 + m;
    const float bb = bias[col];
    float s = 0.f, qq = 0.f;
    #pragma unroll
    for (int i = 0; i < 4; ++i) {
      int r = m0 + stripe * 16 + q * 4 + i;
      if (r < NN) {
        float o = acc[j][i] + bb;
        zb[((size_t)r << 7) + col] = (_Float16)o;
        s += o; qq += o * o;
      }
    }
    red_s[col * 9 + sl] = s;
    red_q[col * 9 + sl] = qq;
  }
  __syncthreads();
  if (tid < 128) {
    float s = 0.f, qq = 0.f;
    #pragma unroll
    for (int k = 0; k < 8; ++k) {
      s += red_s[tid * 9 + k];
      qq += red_q[tid * 9 + k];
    }
    float* pb = ps + (blockIdx.x & (NBUCK - 1)) * 256;
    atomicAdd(&pb[tid], s);
    atomicAdd(&pb[128 + tid], qq);
  }
}

// ---------------- FUSED2: BN-finalize (per-block, 16 buckets) + affine+relu ------
__global__ __launch_bounds__(512) void k_fused2(
    const _Float16* __restrict__ zb, const float* __restrict__ ps,
    const float* __restrict__ gamma, const float* __restrict__ beta,
    const __bf16* __restrict__ wf, const float* __restrict__ bias,
    _Float16* __restrict__ hb, const int* __restrict__ batch,
    float* __restrict__ pooled, int layer)
{
  __shared__ float zs[64][132];
  __shared__ float sab[256];
  const int tid = threadIdx.x;
  const int m0 = blockIdx.x * 64;

  // ---- phase 0: BN finalize from bucketed atomic sums (16 KB, L2-resident) ----
  if (tid < 128) {
    float s = 0.f, q = 0.f;
    #pragma unroll
    for (int b = 0; b < NBUCK; ++b) {
      s += ps[b * 256 + tid];
      q += ps[b * 256 + 128 + tid];
    }
    float mean = s * (1.f / NN);
    float var = q * (1.f / NN) - mean * mean;
    float rstd = rsqrtf(var + 1e-5f);
    float a = gamma[tid] * rstd;
    sab[tid] = a;
    sab[128 + tid] = beta[tid] - mean * a;
  }
  __syncthreads();

  // ---- phase 1: coalesced fp16 load + vector affine + relu -> zs ----
  {
    const int lr = tid >> 3;     // 0..63
    const int sub = tid & 7;     // 16 cols
    const int r = m0 + lr;
    const int c0 = sub << 4;
    h16x8 u0 = {}, u1 = {};
    if (r < NN) {
      const _Float16* rp = zb + ((size_t)r << 7) + c0;
      u0 = *(const h16x8*)rp;
      u1 = *(const h16x8*)(rp + 8);
    }
    float4 v0 = make_float4((float)u0[0], (float)u0[1], (float)u0[2], (float)u0[3]);
    float4 v1 = make_float4((float)u0[4], (float)u0[5], (float)u0[6], (float)u0[7]);
    float4 v2 = make_float4((float)u1[0], (float)u1[1], (float)u1[2], (float)u1[3]);
    float4 v3 = make_float4((float)u1[4], (float)u1[5], (float)u1[6], (float)u1[7]);
    float4 s0 = *(float4*)&sab[c0], s1 = *(float4*)&sab[c0 + 4];
    float4 s2 = *(float4*)&sab[c0 + 8], s3 = *(float4*)&sab[c0 + 12];
    float4 o0 = *(float4*)&sab[128 + c0], o1 = *(float4*)&sab[128 + c0 + 4];
    float4 o2 = *(float4*)&sab[128 + c0 + 8], o3 = *(float4*)&sab[128 + c0 + 12];
    float4 y0, y1, y2, y3;
    y0.x = fmaxf(fmaf(s0.x, v0.x, o0.x), 0.f); y0.y = fmaxf(fmaf(s0.y, v0.y, o0.y), 0.f);
    y0.z = fmaxf(fmaf(s0.z, v0.z, o0.z), 0.f); y0.w = fmaxf(fmaf(s0.w, v0.w, o0.w), 0.f);
    y1.x = fmaxf(fmaf(s1.x, v1.x, o1.x), 0.f); y1.y = fmaxf(fmaf(s1.y, v1.y, o1.y), 0.f);
    y1.z = fmaxf(fmaf(s1.z, v1.z, o1.z), 0.f); y1.w = fmaxf(fmaf(s1.w, v1.w, o1.w), 0.f);
    y2.x = fmaxf(fmaf(s2.x, v2.x, o2.x), 0.f); y2.y = fmaxf(fmaf(s2.y, v2.y, o2.y), 0.f);
    y2.z = fmaxf(fmaf(s2.z, v2.z, o2.z), 0.f); y2.w = fmaxf(fmaf(s2.w, v2.w, o2.w), 0.f);
    y3.x = fmaxf(fmaf(s3.x, v3.x, o3.x), 0.f); y3.y = fmaxf(fmaf(s3.y, v3.y, o3.y), 0.f);
    y3.z = fmaxf(fmaf(s3.z, v3.z, o3.z), 0.f); y3.w = fmaxf(fmaf(s3.w, v3.w, o3.w), 0.f);
    *(float4*)&zs[lr][c0 + 0] = y0;
    *(float4*)&zs[lr][c0 + 4] = y1;
    *(float4*)&zs[lr][c0 + 8] = y2;
    *(float4*)&zs[lr][c0 + 12] = y3;
  }
  __syncthreads();

  // ---- phase 2: MFMA (barrier-free B) ----
  const int wv = tid >> 6, stripe = wv >> 1, half = wv & 1;
  const int lane = tid & 63, q = lane >> 4, m = lane & 15;
  f32x4 acc[4] = {};
  mfma_phase(tid, wf, zs, acc);

  // ---- epilogue: bias+relu, fp16 h store, pooling ----
  int bg[4];
  #pragma unroll
  for (int i = 0; i < 4; ++i) {
    int r = m0 + stripe * 16 + q * 4 + i;
    bg[i] = (r < NN) ? batch[r] : -1;
  }
  #pragma unroll
  for (int ct = 0; ct < 4; ++ct) {
    const int col = half * 64 + ct * 16 + m;
    const float bb = bias[col];
    #pragma unroll
    for (int i = 0; i < 4; ++i) {
      int r = m0 + stripe * 16 + q * 4 + i;
      float v = fmaxf(acc[ct][i] + bb, 0.f);
      acc[ct][i] = v;
      if (r < NN) hb[((size_t)r << 7) + col] = (_Float16)v;
    }
  }

  int gstart = batch[m0];
  int gend = batch[(m0 + 63 < NN) ? (m0 + 63) : (NN - 1)];
  float* red_s = (float*)zs;          // 128*17
  float* red_m = red_s + 2176;        // 128*17
  const int sl = stripe * 4 + q;
  for (int g = gstart; g <= gend; ++g) {
    __syncthreads();
    #pragma unroll
    for (int ct = 0; ct < 4; ++ct) {
      const int col = half * 64 + ct * 16 + m;
      float s = 0.f, mx = 0.f;
      #pragma unroll
      for (int i = 0; i < 4; ++i) {
        if (bg[i] == g) { s += acc[ct][i]; mx = fmaxf(mx, acc[ct][i]); }
      }
      red_s[col * 17 + sl] = s;
      red_m[col * 17 + sl] = mx;
    }
    __syncthreads();
    if (tid < 128) {
      float s = 0.f, mx = 0.f;
      #pragma unroll
      for (int k = 0; k < 16; ++k) {
        s += red_s[tid * 17 + k];
        mx = fmaxf(mx, red_m[tid * 17 + k]);
      }
      if (s != 0.f) atomicAdd(&pooled[g * 1792 + layer * 128 + tid], s);
      if (mx != 0.f)
        atomicMax((int*)&pooled[g * 1792 + 896 + layer * 128 + tid], __float_as_int(mx));
    }
  }
}

// ---------------- Wl1 prep: transpose + split via LDS tiles ----------------
__global__ __launch_bounds__(256) void k_wl1prep(
    const float* __restrict__ Wl1, __bf16* __restrict__ wh, __bf16* __restrict__ wl) {
  __shared__ float tile[32][33];
  const int k0 = blockIdx.x * 32, n0 = blockIdx.y * 32;
  const int lr = threadIdx.x >> 5, lc = threadIdx.x & 31;
  #pragma unroll
  for (int it = 0; it < 4; ++it) {
    int rr = lr + it * 8;
    tile[rr][lc] = Wl1[(size_t)(k0 + rr) * 1792 + n0 + lc];
  }
  __syncthreads();
  #pragma unroll
  for (int it = 0; it < 4; ++it) {
    int rr = lr + it * 8;
    float v = tile[lc][rr];
    __bf16 h = (__bf16)v;
    wh[(size_t)(n0 + rr) * 1792 + k0 + lc] = h;
    wl[(size_t)(n0 + rr) * 1792 + k0 + lc] = (__bf16)(v - (float)h);
  }
}

// ---------------- MLP1 (MFMA split-bf16, split-K=4): part = pooled @ Wl1 ----------
__global__ __launch_bounds__(256) void k_mlp1a(
    const float* __restrict__ P, const __bf16* __restrict__ wh,
    const __bf16* __restrict__ wl, float* __restrict__ part)
{
  const int tid = threadIdx.x;
  const int n0 = blockIdx.x * 64;
  const int m0 = blockIdx.y * 64;
  const int kc = blockIdx.z;          // 0..3, chunk of 448 k
  const int kbase = kc * 448;
  const int w = tid >> 6, lane = tid & 63, q = lane >> 4, m = lane & 15;
  const int row = m0 + w * 16 + m;    // < 256 always
  f32x4 acc[4] = {};
  const float* rp = P + (size_t)row * 1792;
  #pragma unroll 2
  for (int ks = 0; ks < 14; ++ks) {
    const int k0 = kbase + ks * 32 + q * 8;
    float4 v0 = ld4(rp + k0), v1 = ld4(rp + k0 + 4);
    bf16x8 ah, al;
    split8(v0, v1, ah, al);
    #pragma unroll
    for (int ct = 0; ct < 4; ++ct) {
      const int n = n0 + ct * 16 + m;
      bf16x8 bh = *(const bf16x8*)(wh + (size_t)n * 1792 + k0);
      bf16x8 bl = *(const bf16x8*)(wl + (size_t)n * 1792 + k0);
      acc[ct] = __builtin_amdgcn_mfma_f32_16x16x32_bf16(ah, bh, acc[ct], 0, 0, 0);
      acc[ct] = __builtin_amdgcn_mfma_f32_16x16x32_bf16(ah, bl, acc[ct], 0, 0, 0);
      acc[ct] = __builtin_amdgcn_mfma_f32_16x16x32_bf16(al, bh, acc[ct], 0, 0, 0);
    }
  }
  float* pp = part + (size_t)kc * 458752;
  #pragma unroll
  for (int ct = 0; ct < 4; ++ct) {
    const int n = n0 + ct * 16 + m;
    #pragma unroll
    for (int i = 0; i < 4; ++i) {
      int r = m0 + w * 16 + q * 4 + i;
      pp[(size_t)r * 1792 + n] = acc[ct][i];
    }
  }
}

// ---------------- MLP2 (merged: relu(part-sum + bl1) dot Wl2, per-group) ---------
__global__ void k_mlp2(const float* __restrict__ part, const float* __restrict__ bl1,
                       const float* __restrict__ Wl2, const float* __restrict__ bl2,
                       float* __restrict__ out) {
  __shared__ float red[256];
  int g = blockIdx.x, t = threadIdx.x;
  float p = 0.f;
  for (int k = t; k < 1792; k += 256) {
    size_t idx = (size_t)g * 1792 + k;
    float s = bl1[k];
    #pragma unroll
    for (int kc = 0; kc < 4; ++kc) s += part[(size_t)kc * 458752 + idx];
    p += fmaxf(s, 0.f) * Wl2[k];
  }
  red[t] = p;
  __syncthreads();
  for (int s = 128; s > 0; s >>= 1) {
    if (t < s) red[t] += red[t + s];
    __syncthreads();
  }
  if (t == 0) {
    float l = red[0] + bl2[0];
    out[g] = 1.f / (1.f + expf(-l));
    out[NG + g] = l;
  }
}

// ---------------- launch ----------------
extern "C" void kernel_launch(void* const* d_in, const int* in_sizes, int n_in,
                              void* d_out, int out_size, void* d_ws, size_t ws_size,
                              hipStream_t stream) {
  const float* x     = (const float*)d_in[0];
  const int*   edge  = (const int*)d_in[1];
  const int*   batch = (const int*)d_in[2];
  const float* W1    = (const float*)d_in[3];
  const float* b1    = (const float*)d_in[4];
  const float* gamma = (const float*)d_in[5];
  const float* beta  = (const float*)d_in[6];
  const float* W2    = (const float*)d_in[7];
  const float* b2    = (const float*)d_in[8];
  const float* Wl1   = (const float*)d_in[9];
  const float* bl1   = (const float*)d_in[10];
  const float* Wl2   = (const float*)d_in[11];
  const float* bl2   = (const float*)d_in[12];
  float* out = (float*)d_out;

  int* wsi = (int*)d_ws;
  int* row_ptr = wsi;                 // 50048
  int* counts  = wsi + 50048;         // 50048
  int* bsum    = wsi + 100096;        // 256
  int* boff    = wsi + 100352;        // 256
  int* gcur    = wsi + 100608;        // 64 (pad to 100864)
  unsigned short* csr16 = (unsigned short*)(wsi + 100864);  // 800000 u16
  float* wsf   = (float*)(wsi + 950912);
  // float-region layout:
  _Float16* zb     = (_Float16*)wsf;            // [50000,128] fp16 z1 (3.2M floats)
  _Float16* hb     = (_Float16*)(wsf + 6400000);// [50000,128] fp16 h (3.2M floats)
  float*    part   = wsf + 9600000;             // [4][256][1792] (MLP head only)
  float*    psums  = wsf + 12800000;            // [7][16][2][128] bucketed BN sums
  float*    pooled = wsf + 13000448;            // [256,1792] -> ends 13459200
  __bf16*   w1f    = (__bf16*)(wsf + 13459200); // 7*32768 bf16 frag-ordered
  __bf16*   w2f    = (__bf16*)(wsf + 13573888); // 7*32768 bf16 -> ends 13688576
  // bins aliases zb region (dead until first fused1; binB completes before layers)
  unsigned int* bins = (unsigned int*)wsf;      // 49*18432 u32 = 3.6 MB << zb size
  // post-layer aliases (zb region dead after last k_fused2):
  __bf16*   wl1h   = (__bf16*)wsf;              // 1792*1792 bf16
  __bf16*   wl1l   = (__bf16*)(wsf + 1605632);  // ends 3,211,264

  // prep: zeros + x->fp16 + frag-ordered W split; degree hist; CSR scan; binned fill
  k_init<<<25000, 256, 0, stream>>>(x, W1, W2, counts, gcur, pooled, hb, w1f, w2f,
                                    psums);
  k_hist<<<3125, 256, 0, stream>>>(edge, counts);
  k_part<<<196, 256, 0, stream>>>(counts, bsum);
  k_bscan<<<1, 256, 0, stream>>>(bsum, boff, row_ptr);
  k_rowptr<<<196, 256, 0, stream>>>(counts, boff, row_ptr);
  k_binA<<<256, 256, 0, stream>>>(edge, gcur, bins);
  k_binB<<<49, 512, 0, stream>>>(row_ptr, gcur, bins, csr16);

  for (int i = 0; i < NLAY; ++i) {
    k_fused1<<<NBLK1, 512, 0, stream>>>(hb, row_ptr, csr16, w1f + i * 32768,
                                        b1 + i * 128, zb, psums + i * NBUCK * 256);
    k_fused2<<<NBLK, 512, 0, stream>>>(zb, psums + i * NBUCK * 256, gamma + i * 128,
                                       beta + i * 128, w2f + i * 32768,
                                       b2 + i * 128, hb, batch, pooled, i);
  }
  // MLP head (zb region reused for Wl1 split)
  k_wl1prep<<<dim3(56, 56), 256, 0, stream>>>(Wl1, wl1h, wl1l);
  k_mlp1a<<<dim3(28, 4, 4), 256, 0, stream>>>(pooled, wl1h, wl1l, part);
  k_mlp2<<<256, 256, 0, stream>>>(part, bl1, Wl2, bl2, out);
}

// Round 12
// 616.530 us; speedup vs baseline: 1.2626x; 1.0145x over previous
//
#include <hip/hip_runtime.h>
#include <cstdint>
#include <cstddef>

#define NN 50000
#define NE 800000
#define NG 256
#define NLAY 7
#define NBLK1 1563 // 32-row tiles (fused1 AND fused2)
#define NBUCK 16   // BN atomic buckets (contention 1563 -> ~98 per address)
#define CAP 18432  // bins capacity per dst-range

typedef float f32x4 __attribute__((ext_vector_type(4)));
typedef __bf16 bf16x8 __attribute__((ext_vector_type(8)));
typedef _Float16 h16x8 __attribute__((ext_vector_type(8)));

__device__ __forceinline__ float4 ld4(const float* p) { return *(const float4*)p; }
__device__ __forceinline__ void addh8(float4& x, float4& y, h16x8 v) {
  x.x += (float)v[0]; x.y += (float)v[1]; x.z += (float)v[2]; x.w += (float)v[3];
  y.x += (float)v[4]; y.y += (float)v[5]; y.z += (float)v[6]; y.w += (float)v[7];
}

// ---------------- init: zeros + hb=fp16(x) + W1/W2 -> MFMA-fragment order --------
// wf layout: pos = ((kc*16 + slot)*64 + lane)*8 + j, slot = (half*4+ct)*2 + hl.
__global__ void k_init(const float* __restrict__ x, const float* __restrict__ W1,
                       const float* __restrict__ W2, int* __restrict__ counts,
                       int* __restrict__ gcur, float* __restrict__ pooled,
                       _Float16* __restrict__ hb,
                       __bf16* __restrict__ w1f, __bf16* __restrict__ w2f,
                       float* __restrict__ psums) {
  int i = blockIdx.x * 256 + threadIdx.x;  // grid 25000 -> 6.4M
  if (i < NN) counts[i] = 0;
  if (i < 49) gcur[i] = i * CAP;
  if (i < NLAY * NBUCK * 256) psums[i] = 0.f;  // per-layer bucketed BN accumulators
  if (i < NG * 1792) pooled[i] = 0.f;
  if (i < NN * 128) hb[i] = (_Float16)x[i];
  if (i < NLAY * 32768) {
    int l = i >> 15, pos = i & 32767;
    int j = pos & 7, ln = (pos >> 3) & 63, slot = (pos >> 9) & 15, kc = pos >> 13;
    int hl = slot & 1, ctp = (slot >> 1) & 3, hfp = slot >> 3;
    int n = hfp * 64 + ctp * 16 + (ln & 15);
    int k = kc * 32 + ((ln >> 4) << 3) + j;
    float a = W1[l * 16384 + k * 128 + n];
    float b = W2[l * 16384 + k * 128 + n];
    __bf16 ah = (__bf16)a, bh = (__bf16)b;
    w1f[i] = hl ? (__bf16)(a - (float)ah) : ah;
    w2f[i] = hl ? (__bf16)(b - (float)bh) : bh;
  }
}

__global__ void k_hist(const int* __restrict__ edge, int* __restrict__ counts) {
  int e = blockIdx.x * 256 + threadIdx.x;
  if (e < NE) atomicAdd(&counts[edge[NE + e]], 1);
}

// ---------------- parallel CSR scan ----------------
__global__ void k_part(const int* __restrict__ counts, int* __restrict__ bsum) {
  __shared__ int sm[256];
  int b = blockIdx.x, t = threadIdx.x;
  int i = b * 256 + t;
  sm[t] = (i < NN) ? counts[i] : 0;
  __syncthreads();
  for (int s = 128; s > 0; s >>= 1) {
    if (t < s) sm[t] += sm[t + s];
    __syncthreads();
  }
  if (t == 0) bsum[b] = sm[0];
}

__global__ void k_bscan(const int* __restrict__ bsum, int* __restrict__ boff,
                        int* __restrict__ row_ptr) {
  __shared__ int sm[256];
  int t = threadIdx.x;
  int v = (t < 196) ? bsum[t] : 0;
  sm[t] = v;
  __syncthreads();
  int val = v;
  for (int off = 1; off < 256; off <<= 1) {
    int o = (t >= off) ? sm[t - off] : 0;
    __syncthreads();
    val += o;
    sm[t] = val;
    __syncthreads();
  }
  if (t < 196) boff[t] = val - v;  // exclusive
  if (t == 255) row_ptr[NN] = val; // total = NE
}

__global__ void k_rowptr(const int* __restrict__ counts, const int* __restrict__ boff,
                         int* __restrict__ row_ptr) {
  __shared__ int sm[256];
  int b = blockIdx.x, t = threadIdx.x;
  int i = b * 256 + t;
  int c = (i < NN) ? counts[i] : 0;
  sm[t] = c;
  __syncthreads();
  int val = c;
  for (int off = 1; off < 256; off <<= 1) {
    int o = (t >= off) ? sm[t - off] : 0;
    __syncthreads();
    val += o;
    sm[t] = val;
    __syncthreads();
  }
  if (i < NN) row_ptr[i] = val - c + boff[b];
}

// ---------------- binned CSR build ----------------
__global__ __launch_bounds__(256) void k_binA(const int* __restrict__ edge,
                                              int* __restrict__ gcur,
                                              unsigned int* __restrict__ bins) {
  __shared__ int lh[49], lbase[49], lt[49];
  const int tid = threadIdx.x;
  const int e0 = blockIdx.x * 3125, e1 = e0 + 3125;
  if (tid < 49) { lh[tid] = 0; lt[tid] = 0; }
  __syncthreads();
  for (int e = e0 + tid; e < e1; e += 256)
    atomicAdd(&lh[edge[NE + e] >> 10], 1);
  __syncthreads();
  if (tid < 49) lbase[tid] = atomicAdd(&gcur[tid], lh[tid]);
  __syncthreads();
  for (int e = e0 + tid; e < e1; e += 256) {
    int dst = edge[NE + e], src = edge[e];
    int r = dst >> 10;
    int t = atomicAdd(&lt[r], 1);
    bins[lbase[r] + t] = ((unsigned)dst << 16) | (unsigned)src;
  }
}

__global__ __launch_bounds__(512) void k_binB(const int* __restrict__ row_ptr,
                                              const int* __restrict__ gcur,
                                              const unsigned int* __restrict__ bins,
                                              unsigned short* __restrict__ csr16) {
  __shared__ int lcur[1024];
  __shared__ unsigned short lcsr[24576];  // 48 KB
  const int blk = blockIdx.x, tid = threadIdx.x;
  const int base = blk << 10;
  const int nn = (base + 1024 <= NN) ? 1024 : (NN - base);
  const int seg0 = row_ptr[base];
  const int seg1 = row_ptr[(base + 1024 <= NN) ? (base + 1024) : NN];
  for (int i = tid; i < nn; i += 512) lcur[i] = row_ptr[base + i] - seg0;
  __syncthreads();
  const int tot = gcur[blk] - blk * CAP;
  for (int t = tid; t < tot; t += 512) {
    unsigned int p = bins[blk * CAP + t];
    int dst = (int)(p >> 16), src = (int)(p & 0xffffu);
    int pos = atomicAdd(&lcur[dst - base], 1);
    lcsr[pos] = (unsigned short)src;
  }
  __syncthreads();
  for (int i = tid; i < seg1 - seg0; i += 512) csr16[seg0 + i] = lcsr[i];
}

// ---------------- split fp32x8 -> bf16 hi/lo fragments ----------------
__device__ __forceinline__ void split8(const float4 v0, const float4 v1,
                                       bf16x8& hi, bf16x8& lo) {
  float f[8] = {v0.x, v0.y, v0.z, v0.w, v1.x, v1.y, v1.z, v1.w};
  #pragma unroll
  for (int j = 0; j < 8; ++j) {
    __bf16 h = (__bf16)f[j];
    hi[j] = h;
    lo[j] = (__bf16)(f[j] - (float)h);
  }
}

// ---------------- MFMA phase (M=32, 8 waves, acc[2]) shared by fused1/fused2 ----
__device__ __forceinline__ void mfma_phase32(
    int tid, const __bf16* __restrict__ wf, float (*zs)[132], f32x4 acc[2])
{
  const int wv = tid >> 6;
  const int stripe = wv >> 2, half = (wv >> 1) & 1, cpair = wv & 1;
  const int lane = tid & 63, q = lane >> 4, m = lane & 15;
  #pragma unroll
  for (int kc = 0; kc < 4; ++kc) {
    const int k0 = kc * 32 + q * 8;
    float4 v0 = *(const float4*)&zs[stripe * 16 + m][k0];
    float4 v1 = *(const float4*)&zs[stripe * 16 + m][k0 + 4];
    bf16x8 ah, al;
    split8(v0, v1, ah, al);
    #pragma unroll
    for (int j = 0; j < 2; ++j) {
      const int ct = cpair * 2 + j;
      const int sbase = (half * 4 + ct) * 2;
      const __bf16* bp = wf + (((size_t)(kc * 16 + sbase) * 64 + lane) << 3);
      bf16x8 bh = *(const bf16x8*)bp;
      bf16x8 bl = *(const bf16x8*)(bp + 512);  // slot+1 = +64 lanes * 8
      acc[j] = __builtin_amdgcn_mfma_f32_16x16x32_bf16(ah, bh, acc[j], 0, 0, 0);
      acc[j] = __builtin_amdgcn_mfma_f32_16x16x32_bf16(ah, bl, acc[j], 0, 0, 0);
      acc[j] = __builtin_amdgcn_mfma_f32_16x16x32_bf16(al, bh, acc[j], 0, 0, 0);
    }
  }
  __syncthreads();  // zs dead after; callers reuse as scratch
}

// ---------------- FUSED1 v4: 32-row tile, 8-edge ILP + 4/2/1 tail cascade -------
// Bucketed BN atomics (R8 lesson: single-buffer atomics = +18us RMW serialization).
__global__ __launch_bounds__(512, 8) void k_fused1(
    const _Float16* __restrict__ hb, const int* __restrict__ row_ptr,
    const unsigned short* __restrict__ csr_src, const __bf16* __restrict__ wf,
    const float* __restrict__ bias, _Float16* __restrict__ zb,
    float* __restrict__ ps)   // ps = psums + layer*NBUCK*256; bucket b at ps+b*256
{
  __shared__ float zs[32][132];
  const int tid = threadIdx.x;
  const int m0 = blockIdx.x * 32;

  // ---- phase 1: gather agg = h[r] + sum h[src] ----
  {
    const int lr = tid >> 4;     // 0..31 rows
    const int sub = tid & 15;    // 8 cols each
    const int r = m0 + lr;
    const int c0 = sub << 3;
    float4 a0 = make_float4(0.f, 0.f, 0.f, 0.f), a1 = a0;
    if (r < NN) {
      addh8(a0, a1, *(const h16x8*)(hb + ((size_t)r << 7) + c0));
      int e = row_ptr[r], e1 = row_ptr[r + 1];
      for (; e + 7 < e1; e += 8) {
        const h16x8 v0 = *(const h16x8*)(hb + ((size_t)csr_src[e + 0] << 7) + c0);
        const h16x8 v1 = *(const h16x8*)(hb + ((size_t)csr_src[e + 1] << 7) + c0);
        const h16x8 v2 = *(const h16x8*)(hb + ((size_t)csr_src[e + 2] << 7) + c0);
        const h16x8 v3 = *(const h16x8*)(hb + ((size_t)csr_src[e + 3] << 7) + c0);
        const h16x8 v4 = *(const h16x8*)(hb + ((size_t)csr_src[e + 4] << 7) + c0);
        const h16x8 v5 = *(const h16x8*)(hb + ((size_t)csr_src[e + 5] << 7) + c0);
        const h16x8 v6 = *(const h16x8*)(hb + ((size_t)csr_src[e + 6] << 7) + c0);
        const h16x8 v7 = *(const h16x8*)(hb + ((size_t)csr_src[e + 7] << 7) + c0);
        // fp16 pairwise tree (3 deep, values O(1): err ~1e-2 abs per group)
        h16x8 t0 = v0 + v1, t1 = v2 + v3, t2 = v4 + v5, t3 = v6 + v7;
        h16x8 u0 = t0 + t1, u1 = t2 + t3;
        addh8(a0, a1, u0 + u1);
      }
      if (e + 3 < e1) {
        const h16x8 v0 = *(const h16x8*)(hb + ((size_t)csr_src[e + 0] << 7) + c0);
        const h16x8 v1 = *(const h16x8*)(hb + ((size_t)csr_src[e + 1] << 7) + c0);
        const h16x8 v2 = *(const h16x8*)(hb + ((size_t)csr_src[e + 2] << 7) + c0);
        const h16x8 v3 = *(const h16x8*)(hb + ((size_t)csr_src[e + 3] << 7) + c0);
        h16x8 t0 = v0 + v1, t1 = v2 + v3;
        addh8(a0, a1, t0 + t1);
        e += 4;
      }
      if (e + 1 < e1) {
        const h16x8 v0 = *(const h16x8*)(hb + ((size_t)csr_src[e + 0] << 7) + c0);
        const h16x8 v1 = *(const h16x8*)(hb + ((size_t)csr_src[e + 1] << 7) + c0);
        addh8(a0, a1, v0 + v1);
        e += 2;
      }
      if (e < e1)
        addh8(a0, a1, *(const h16x8*)(hb + ((size_t)csr_src[e] << 7) + c0));
    }
    *(float4*)&zs[lr][c0 + 0] = a0;
    *(float4*)&zs[lr][c0 + 4] = a1;
  }
  __syncthreads();

  // ---- phase 2: MFMA M=32 ----
  const int wv = tid >> 6;
  const int stripe = wv >> 2, half = (wv >> 1) & 1, cpair = wv & 1;
  const int lane = tid & 63, q = lane >> 4, m = lane & 15;
  f32x4 acc[2] = {};
  mfma_phase32(tid, wf, zs, acc);

  // ---- epilogue: bias, fp16 z1 store, BN partials (8 slots/col) ----
  float* red_s = (float*)zs;          // 128*9
  float* red_q = red_s + 1152;        // 128*9
  const int sl = stripe * 4 + q;      // 0..7
  #pragma unroll
  for (int j = 0; j < 2; ++j) {
    const int ct = cpair * 2 + j;
    const int col = half * 64 + ct * 16 + m;
    const float bb = bias[col];
    float s = 0.f, qq = 0.f;
    #pragma unroll
    for (int i = 0; i < 4; ++i) {
      int r = m0 + stripe * 16 + q * 4 + i;
      if (r < NN) {
        float o = acc[j][i] + bb;
        zb[((size_t)r << 7) + col] = (_Float16)o;
        s += o; qq += o * o;
      }
    }
    red_s[col * 9 + sl] = s;
    red_q[col * 9 + sl] = qq;
  }
  __syncthreads();
  if (tid < 128) {
    float s = 0.f, qq = 0.f;
    #pragma unroll
    for (int k = 0; k < 8; ++k) {
      s += red_s[tid * 9 + k];
      qq += red_q[tid * 9 + k];
    }
    float* pb = ps + (blockIdx.x & (NBUCK - 1)) * 256;
    atomicAdd(&pb[tid], s);
    atomicAdd(&pb[128 + tid], qq);
  }
}

// ---------------- FUSED2 v2: 32-row tile (grid 1563) --------------------------
// R9 theory: fused2 ~40us at grid 782 (3.05 blocks/CU) is latency-bound across
// its 5 barrier-phases, same diagnosis as R5 fused1. Mirror the 32-row transform:
// 2x blocks in flight, half the LDS, same math.
__global__ __launch_bounds__(512) void k_fused2(
    const _Float16* __restrict__ zb, const float* __restrict__ ps,
    const float* __restrict__ gamma, const float* __restrict__ beta,
    const __bf16* __restrict__ wf, const float* __restrict__ bias,
    _Float16* __restrict__ hb, const int* __restrict__ batch,
    float* __restrict__ pooled, int layer)
{
  __shared__ float zs[32][132];
  __shared__ float sab[256];
  const int tid = threadIdx.x;
  const int m0 = blockIdx.x * 32;

  // ---- phase 0: BN finalize from bucketed atomic sums (16 KB, L2-resident) ----
  if (tid < 128) {
    float s = 0.f, q = 0.f;
    #pragma unroll
    for (int b = 0; b < NBUCK; ++b) {
      s += ps[b * 256 + tid];
      q += ps[b * 256 + 128 + tid];
    }
    float mean = s * (1.f / NN);
    float var = q * (1.f / NN) - mean * mean;
    float rstd = rsqrtf(var + 1e-5f);
    float a = gamma[tid] * rstd;
    sab[tid] = a;
    sab[128 + tid] = beta[tid] - mean * a;
  }
  __syncthreads();

  // ---- phase 1: coalesced fp16 load + vector affine + relu -> zs ----
  {
    const int lr = tid >> 4;     // 0..31 rows
    const int sub = tid & 15;    // 8 cols
    const int r = m0 + lr;
    const int c0 = sub << 3;
    h16x8 u0 = {};
    if (r < NN) u0 = *(const h16x8*)(zb + ((size_t)r << 7) + c0);
    float4 v0 = make_float4((float)u0[0], (float)u0[1], (float)u0[2], (float)u0[3]);
    float4 v1 = make_float4((float)u0[4], (float)u0[5], (float)u0[6], (float)u0[7]);
    float4 s0 = *(float4*)&sab[c0], s1 = *(float4*)&sab[c0 + 4];
    float4 o0 = *(float4*)&sab[128 + c0], o1 = *(float4*)&sab[128 + c0 + 4];
    float4 y0, y1;
    y0.x = fmaxf(fmaf(s0.x, v0.x, o0.x), 0.f); y0.y = fmaxf(fmaf(s0.y, v0.y, o0.y), 0.f);
    y0.z = fmaxf(fmaf(s0.z, v0.z, o0.z), 0.f); y0.w = fmaxf(fmaf(s0.w, v0.w, o0.w), 0.f);
    y1.x = fmaxf(fmaf(s1.x, v1.x, o1.x), 0.f); y1.y = fmaxf(fmaf(s1.y, v1.y, o1.y), 0.f);
    y1.z = fmaxf(fmaf(s1.z, v1.z, o1.z), 0.f); y1.w = fmaxf(fmaf(s1.w, v1.w, o1.w), 0.f);
    *(float4*)&zs[lr][c0 + 0] = y0;
    *(float4*)&zs[lr][c0 + 4] = y1;
  }
  __syncthreads();

  // ---- phase 2: MFMA M=32 ----
  const int wv = tid >> 6;
  const int stripe = wv >> 2, half = (wv >> 1) & 1, cpair = wv & 1;
  const int lane = tid & 63, q = lane >> 4, m = lane & 15;
  f32x4 acc[2] = {};
  mfma_phase32(tid, wf, zs, acc);

  // ---- epilogue: bias+relu, fp16 h store, pooling ----
  int bg[4];
  #pragma unroll
  for (int i = 0; i < 4; ++i) {
    int r = m0 + stripe * 16 + q * 4 + i;
    bg[i] = (r < NN) ? batch[r] : -1;
  }
  #pragma unroll
  for (int j = 0; j < 2; ++j) {
    const int ct = cpair * 2 + j;
    const int col = half * 64 + ct * 16 + m;
    const float bb = bias[col];
    #pragma unroll
    for (int i = 0; i < 4; ++i) {
      int r = m0 + stripe * 16 + q * 4 + i;
      float v = fmaxf(acc[j][i] + bb, 0.f);
      acc[j][i] = v;
      if (r < NN) hb[((size_t)r << 7) + col] = (_Float16)v;
    }
  }

  int gstart = batch[m0];
  int gend = batch[(m0 + 31 < NN) ? (m0 + 31) : (NN - 1)];
  float* red_s = (float*)zs;          // 128*9
  float* red_m = red_s + 1152;        // 128*9
  const int sl = stripe * 4 + q;      // 0..7
  for (int g = gstart; g <= gend; ++g) {
    __syncthreads();
    #pragma unroll
    for (int j = 0; j < 2; ++j) {
      const int ct = cpair * 2 + j;
      const int col = half * 64 + ct * 16 + m;
      float s = 0.f, mx = 0.f;
      #pragma unroll
      for (int i = 0; i < 4; ++i) {
        if (bg[i] == g) { s += acc[j][i]; mx = fmaxf(mx, acc[j][i]); }
      }
      red_s[col * 9 + sl] = s;
      red_m[col * 9 + sl] = mx;
    }
    __syncthreads();
    if (tid < 128) {
      float s = 0.f, mx = 0.f;
      #pragma unroll
      for (int k = 0; k < 8; ++k) {
        s += red_s[tid * 9 + k];
        mx = fmaxf(mx, red_m[tid * 9 + k]);
      }
      if (s != 0.f) atomicAdd(&pooled[g * 1792 + layer * 128 + tid], s);
      if (mx != 0.f)
        atomicMax((int*)&pooled[g * 1792 + 896 + layer * 128 + tid], __float_as_int(mx));
    }
  }
}

// ---------------- Wl1 prep: transpose + split via LDS tiles ----------------
__global__ __launch_bounds__(256) void k_wl1prep(
    const float* __restrict__ Wl1, __bf16* __restrict__ wh, __bf16* __restrict__ wl) {
  __shared__ float tile[32][33];
  const int k0 = blockIdx.x * 32, n0 = blockIdx.y * 32;
  const int lr = threadIdx.x >> 5, lc = threadIdx.x & 31;
  #pragma unroll
  for (int it = 0; it < 4; ++it) {
    int rr = lr + it * 8;
    tile[rr][lc] = Wl1[(size_t)(k0 + rr) * 1792 + n0 + lc];
  }
  __syncthreads();
  #pragma unroll
  for (int it = 0; it < 4; ++it) {
    int rr = lr + it * 8;
    float v = tile[lc][rr];
    __bf16 h = (__bf16)v;
    wh[(size_t)(n0 + rr) * 1792 + k0 + lc] = h;
    wl[(size_t)(n0 + rr) * 1792 + k0 + lc] = (__bf16)(v - (float)h);
  }
}

// ---------------- MLP1 (MFMA split-bf16, split-K=4): part = pooled @ Wl1 ----------
__global__ __launch_bounds__(256) void k_mlp1a(
    const float* __restrict__ P, const __bf16* __restrict__ wh,
    const __bf16* __restrict__ wl, float* __restrict__ part)
{
  const int tid = threadIdx.x;
  const int n0 = blockIdx.x * 64;
  const int m0 = blockIdx.y * 64;
  const int kc = blockIdx.z;          // 0..3, chunk of 448 k
  const int kbase = kc * 448;
  const int w = tid >> 6, lane = tid & 63, q = lane >> 4, m = lane & 15;
  const int row = m0 + w * 16 + m;    // < 256 always
  f32x4 acc[4] = {};
  const float* rp = P + (size_t)row * 1792;
  #pragma unroll 2
  for (int ks = 0; ks < 14; ++ks) {
    const int k0 = kbase + ks * 32 + q * 8;
    float4 v0 = ld4(rp + k0), v1 = ld4(rp + k0 + 4);
    bf16x8 ah, al;
    split8(v0, v1, ah, al);
    #pragma unroll
    for (int ct = 0; ct < 4; ++ct) {
      const int n = n0 + ct * 16 + m;
      bf16x8 bh = *(const bf16x8*)(wh + (size_t)n * 1792 + k0);
      bf16x8 bl = *(const bf16x8*)(wl + (size_t)n * 1792 + k0);
      acc[ct] = __builtin_amdgcn_mfma_f32_16x16x32_bf16(ah, bh, acc[ct], 0, 0, 0);
      acc[ct] = __builtin_amdgcn_mfma_f32_16x16x32_bf16(ah, bl, acc[ct], 0, 0, 0);
      acc[ct] = __builtin_amdgcn_mfma_f32_16x16x32_bf16(al, bh, acc[ct], 0, 0, 0);
    }
  }
  float* pp = part + (size_t)kc * 458752;
  #pragma unroll
  for (int ct = 0; ct < 4; ++ct) {
    const int n = n0 + ct * 16 + m;
    #pragma unroll
    for (int i = 0; i < 4; ++i) {
      int r = m0 + w * 16 + q * 4 + i;
      pp[(size_t)r * 1792 + n] = acc[ct][i];
    }
  }
}

// ---------------- MLP2 (merged: relu(part-sum + bl1) dot Wl2, per-group) ---------
__global__ void k_mlp2(const float* __restrict__ part, const float* __restrict__ bl1,
                       const float* __restrict__ Wl2, const float* __restrict__ bl2,
                       float* __restrict__ out) {
  __shared__ float red[256];
  int g = blockIdx.x, t = threadIdx.x;
  float p = 0.f;
  for (int k = t; k < 1792; k += 256) {
    size_t idx = (size_t)g * 1792 + k;
    float s = bl1[k];
    #pragma unroll
    for (int kc = 0; kc < 4; ++kc) s += part[(size_t)kc * 458752 + idx];
    p += fmaxf(s, 0.f) * Wl2[k];
  }
  red[t] = p;
  __syncthreads();
  for (int s = 128; s > 0; s >>= 1) {
    if (t < s) red[t] += red[t + s];
    __syncthreads();
  }
  if (t == 0) {
    float l = red[0] + bl2[0];
    out[g] = 1.f / (1.f + expf(-l));
    out[NG + g] = l;
  }
}

// ---------------- launch ----------------
extern "C" void kernel_launch(void* const* d_in, const int* in_sizes, int n_in,
                              void* d_out, int out_size, void* d_ws, size_t ws_size,
                              hipStream_t stream) {
  const float* x     = (const float*)d_in[0];
  const int*   edge  = (const int*)d_in[1];
  const int*   batch = (const int*)d_in[2];
  const float* W1    = (const float*)d_in[3];
  const float* b1    = (const float*)d_in[4];
  const float* gamma = (const float*)d_in[5];
  const float* beta  = (const float*)d_in[6];
  const float* W2    = (const float*)d_in[7];
  const float* b2    = (const float*)d_in[8];
  const float* Wl1   = (const float*)d_in[9];
  const float* bl1   = (const float*)d_in[10];
  const float* Wl2   = (const float*)d_in[11];
  const float* bl2   = (const float*)d_in[12];
  float* out = (float*)d_out;

  int* wsi = (int*)d_ws;
  int* row_ptr = wsi;                 // 50048
  int* counts  = wsi + 50048;         // 50048
  int* bsum    = wsi + 100096;        // 256
  int* boff    = wsi + 100352;        // 256
  int* gcur    = wsi + 100608;        // 64 (pad to 100864)
  unsigned short* csr16 = (unsigned short*)(wsi + 100864);  // 800000 u16
  float* wsf   = (float*)(wsi + 950912);
  // float-region layout:
  _Float16* zb     = (_Float16*)wsf;            // [50000,128] fp16 z1 (3.2M floats)
  _Float16* hb     = (_Float16*)(wsf + 6400000);// [50000,128] fp16 h (3.2M floats)
  float*    part   = wsf + 9600000;             // [4][256][1792] (MLP head only)
  float*    psums  = wsf + 12800000;            // [7][16][2][128] bucketed BN sums
  float*    pooled = wsf + 13000448;            // [256,1792] -> ends 13459200
  __bf16*   w1f    = (__bf16*)(wsf + 13459200); // 7*32768 bf16 frag-ordered
  __bf16*   w2f    = (__bf16*)(wsf + 13573888); // 7*32768 bf16 -> ends 13688576
  // bins aliases zb region (dead until first fused1; binB completes before layers)
  unsigned int* bins = (unsigned int*)wsf;      // 49*18432 u32 = 3.6 MB << zb size
  // post-layer aliases (zb region dead after last k_fused2):
  __bf16*   wl1h   = (__bf16*)wsf;              // 1792*1792 bf16
  __bf16*   wl1l   = (__bf16*)(wsf + 1605632);  // ends 3,211,264

  // prep: zeros + x->fp16 + frag-ordered W split; degree hist; CSR scan; binned fill
  k_init<<<25000, 256, 0, stream>>>(x, W1, W2, counts, gcur, pooled, hb, w1f, w2f,
                                    psums);
  k_hist<<<3125, 256, 0, stream>>>(edge, counts);
  k_part<<<196, 256, 0, stream>>>(counts, bsum);
  k_bscan<<<1, 256, 0, stream>>>(bsum, boff, row_ptr);
  k_rowptr<<<196, 256, 0, stream>>>(counts, boff, row_ptr);
  k_binA<<<256, 256, 0, stream>>>(edge, gcur, bins);
  k_binB<<<49, 512, 0, stream>>>(row_ptr, gcur, bins, csr16);

  for (int i = 0; i < NLAY; ++i) {
    k_fused1<<<NBLK1, 512, 0, stream>>>(hb, row_ptr, csr16, w1f + i * 32768,
                                        b1 + i * 128, zb, psums + i * NBUCK * 256);
    k_fused2<<<NBLK1, 512, 0, stream>>>(zb, psums + i * NBUCK * 256, gamma + i * 128,
                                        beta + i * 128, w2f + i * 32768,
                                        b2 + i * 128, hb, batch, pooled, i);
  }
  // MLP head (zb region reused for Wl1 split)
  k_wl1prep<<<dim3(56, 56), 256, 0, stream>>>(Wl1, wl1h, wl1l);
  k_mlp1a<<<dim3(28, 4, 4), 256, 0, stream>>>(pooled, wl1h, wl1l, part);
  k_mlp2<<<256, 256, 0, stream>>>(part, bl1, Wl2, bl2, out);
}

// Round 13
// 579.749 us; speedup vs baseline: 1.3427x; 1.0634x over previous
//
#include <hip/hip_runtime.h>
#include <cstdint>
#include <cstddef>

#define NN 50000
#define NE 800000
#define NG 256
#define NLAY 7
#define NBLK1 1563 // 32-row tiles (fused1 AND fused2)
#define NBUCK 16   // BN atomic buckets (contention 1563 -> ~98 per address)
#define CAP 18432  // bins capacity per dst-range

typedef float f32x4 __attribute__((ext_vector_type(4)));
typedef __bf16 bf16x8 __attribute__((ext_vector_type(8)));
typedef _Float16 h16x8 __attribute__((ext_vector_type(8)));

__device__ __forceinline__ float4 ld4(const float* p) { return *(const float4*)p; }
__device__ __forceinline__ void addh8(float4& x, float4& y, h16x8 v) {
  x.x += (float)v[0]; x.y += (float)v[1]; x.z += (float)v[2]; x.w += (float)v[3];
  y.x += (float)v[4]; y.y += (float)v[5]; y.z += (float)v[6]; y.w += (float)v[7];
}

// ---------------- init: zeros + hb=fp16(x) + W1/W2 -> MFMA-fragment order --------
// wf layout: pos = ((kc*16 + slot)*64 + lane)*8 + j, slot = (half*4+ct)*2 + hl.
__global__ void k_init(const float* __restrict__ x, const float* __restrict__ W1,
                       const float* __restrict__ W2,
                       int* __restrict__ gcur, float* __restrict__ pooled,
                       _Float16* __restrict__ hb,
                       __bf16* __restrict__ w1f, __bf16* __restrict__ w2f,
                       float* __restrict__ psums) {
  int i = blockIdx.x * 256 + threadIdx.x;  // grid 25000 -> 6.4M
  if (i < 49) gcur[i] = i * CAP;
  if (i < NLAY * NBUCK * 256) psums[i] = 0.f;  // per-layer bucketed BN accumulators
  if (i < NG * 1792) pooled[i] = 0.f;
  if (i < NN * 128) hb[i] = (_Float16)x[i];
  if (i < NLAY * 32768) {
    int l = i >> 15, pos = i & 32767;
    int j = pos & 7, ln = (pos >> 3) & 63, slot = (pos >> 9) & 15, kc = pos >> 13;
    int hl = slot & 1, ctp = (slot >> 1) & 3, hfp = slot >> 3;
    int n = hfp * 64 + ctp * 16 + (ln & 15);
    int k = kc * 32 + ((ln >> 4) << 3) + j;
    float a = W1[l * 16384 + k * 128 + n];
    float b = W2[l * 16384 + k * 128 + n];
    __bf16 ah = (__bf16)a, bh = (__bf16)b;
    w1f[i] = hl ? (__bf16)(a - (float)ah) : ah;
    w2f[i] = hl ? (__bf16)(b - (float)bh) : bh;
  }
}

// ---------------- binned CSR build (A: scatter to 1024-row bins) ----------------
__global__ __launch_bounds__(256) void k_binA(const int* __restrict__ edge,
                                              int* __restrict__ gcur,
                                              unsigned int* __restrict__ bins) {
  __shared__ int lh[49], lbase[49], lt[49];
  const int tid = threadIdx.x;
  const int e0 = blockIdx.x * 3125, e1 = e0 + 3125;
  if (tid < 49) { lh[tid] = 0; lt[tid] = 0; }
  __syncthreads();
  for (int e = e0 + tid; e < e1; e += 256)
    atomicAdd(&lh[edge[NE + e] >> 10], 1);
  __syncthreads();
  if (tid < 49) lbase[tid] = atomicAdd(&gcur[tid], lh[tid]);
  __syncthreads();
  for (int e = e0 + tid; e < e1; e += 256) {
    int dst = edge[NE + e], src = edge[e];
    int r = dst >> 10;
    int t = atomicAdd(&lt[r], 1);
    bins[lbase[r] + t] = ((unsigned)dst << 16) | (unsigned)src;
  }
}

// ---------------- binB v2: per-bin histogram + in-LDS scan -> row_ptr + csr16 ----
// Replaces the 4-kernel hist/part/bscan/rowptr chain (R12: prep ~60us, 5 dependent
// launches). Each bin holds all edges of its 1024-row range, so per-row counts,
// a 1024-wide exclusive scan, and seg0 (prefix of 49 bin totals from gcur) are
// all computable locally. CSR content identical to the old path.
__global__ __launch_bounds__(512) void k_binB(const int* __restrict__ gcur,
                                              const unsigned int* __restrict__ bins,
                                              unsigned short* __restrict__ csr16,
                                              int* __restrict__ row_ptr) {
  __shared__ int lhist[1024];
  __shared__ int lcur[1024];
  __shared__ int sm[512];
  __shared__ unsigned short lcsr[24576];  // 48 KB (LDS total ~58 KB)
  const int blk = blockIdx.x, tid = threadIdx.x;
  const int base = blk << 10;
  const int tot = gcur[blk] - blk * CAP;
  int seg0 = 0;
  for (int k = 0; k < blk; ++k) seg0 += gcur[k] - k * CAP;  // <=48 L1-hot loads
  for (int i = tid; i < 1024; i += 512) lhist[i] = 0;
  __syncthreads();
  // pass 1: per-row histogram
  for (int t = tid; t < tot; t += 512)
    atomicAdd(&lhist[(int)(bins[blk * CAP + t] >> 16) - base], 1);
  __syncthreads();
  // exclusive scan over 1024 rows: 2 elems/thread + 512-wide Hillis-Steele
  int a = lhist[2 * tid], b = lhist[2 * tid + 1];
  int pair = a + b;
  sm[tid] = pair;
  __syncthreads();
  int val = pair;
  for (int off = 1; off < 512; off <<= 1) {
    int o = (tid >= off) ? sm[tid - off] : 0;
    __syncthreads();
    val += o;
    sm[tid] = val;
    __syncthreads();
  }
  int e0 = val - pair;         // exclusive offset of row 2*tid
  int e1 = e0 + a;             // exclusive offset of row 2*tid+1
  lcur[2 * tid] = e0;
  lcur[2 * tid + 1] = e1;
  if (base + 2 * tid < NN)     row_ptr[base + 2 * tid] = seg0 + e0;
  if (base + 2 * tid + 1 < NN) row_ptr[base + 2 * tid + 1] = seg0 + e1;
  if (blk == 48 && tid == 0)   row_ptr[NN] = seg0 + tot;  // = NE
  __syncthreads();
  // pass 2: scatter into compacted per-row segments
  for (int t = tid; t < tot; t += 512) {
    unsigned int p = bins[blk * CAP + t];
    int dst = (int)(p >> 16), src = (int)(p & 0xffffu);
    int pos = atomicAdd(&lcur[dst - base], 1);
    lcsr[pos] = (unsigned short)src;
  }
  __syncthreads();
  for (int i = tid; i < tot; i += 512) csr16[seg0 + i] = lcsr[i];
}

// ---------------- split fp32x8 -> bf16 hi/lo fragments ----------------
__device__ __forceinline__ void split8(const float4 v0, const float4 v1,
                                       bf16x8& hi, bf16x8& lo) {
  float f[8] = {v0.x, v0.y, v0.z, v0.w, v1.x, v1.y, v1.z, v1.w};
  #pragma unroll
  for (int j = 0; j < 8; ++j) {
    __bf16 h = (__bf16)f[j];
    hi[j] = h;
    lo[j] = (__bf16)(f[j] - (float)h);
  }
}

// ---------------- MFMA phase (M=32, 8 waves, acc[2]) shared by fused1/fused2 ----
__device__ __forceinline__ void mfma_phase32(
    int tid, const __bf16* __restrict__ wf, float (*zs)[132], f32x4 acc[2])
{
  const int wv = tid >> 6;
  const int stripe = wv >> 2, half = (wv >> 1) & 1, cpair = wv & 1;
  const int lane = tid & 63, q = lane >> 4, m = lane & 15;
  #pragma unroll
  for (int kc = 0; kc < 4; ++kc) {
    const int k0 = kc * 32 + q * 8;
    float4 v0 = *(const float4*)&zs[stripe * 16 + m][k0];
    float4 v1 = *(const float4*)&zs[stripe * 16 + m][k0 + 4];
    bf16x8 ah, al;
    split8(v0, v1, ah, al);
    #pragma unroll
    for (int j = 0; j < 2; ++j) {
      const int ct = cpair * 2 + j;
      const int sbase = (half * 4 + ct) * 2;
      const __bf16* bp = wf + (((size_t)(kc * 16 + sbase) * 64 + lane) << 3);
      bf16x8 bh = *(const bf16x8*)bp;
      bf16x8 bl = *(const bf16x8*)(bp + 512);  // slot+1 = +64 lanes * 8
      acc[j] = __builtin_amdgcn_mfma_f32_16x16x32_bf16(ah, bh, acc[j], 0, 0, 0);
      acc[j] = __builtin_amdgcn_mfma_f32_16x16x32_bf16(ah, bl, acc[j], 0, 0, 0);
      acc[j] = __builtin_amdgcn_mfma_f32_16x16x32_bf16(al, bh, acc[j], 0, 0, 0);
    }
  }
  __syncthreads();  // zs dead after; callers reuse as scratch
}

// ---------------- FUSED1 v4: 32-row tile, 8-edge ILP + 4/2/1 tail cascade -------
// Bucketed BN atomics (R8 lesson: single-buffer atomics = +18us RMW serialization).
__global__ __launch_bounds__(512, 8) void k_fused1(
    const _Float16* __restrict__ hb, const int* __restrict__ row_ptr,
    const unsigned short* __restrict__ csr_src, const __bf16* __restrict__ wf,
    const float* __restrict__ bias, _Float16* __restrict__ zb,
    float* __restrict__ ps)   // ps = psums + layer*NBUCK*256; bucket b at ps+b*256
{
  __shared__ float zs[32][132];
  const int tid = threadIdx.x;
  const int m0 = blockIdx.x * 32;

  // ---- phase 1: gather agg = h[r] + sum h[src] ----
  {
    const int lr = tid >> 4;     // 0..31 rows
    const int sub = tid & 15;    // 8 cols each
    const int r = m0 + lr;
    const int c0 = sub << 3;
    float4 a0 = make_float4(0.f, 0.f, 0.f, 0.f), a1 = a0;
    if (r < NN) {
      addh8(a0, a1, *(const h16x8*)(hb + ((size_t)r << 7) + c0));
      int e = row_ptr[r], e1 = row_ptr[r + 1];
      for (; e + 7 < e1; e += 8) {
        const h16x8 v0 = *(const h16x8*)(hb + ((size_t)csr_src[e + 0] << 7) + c0);
        const h16x8 v1 = *(const h16x8*)(hb + ((size_t)csr_src[e + 1] << 7) + c0);
        const h16x8 v2 = *(const h16x8*)(hb + ((size_t)csr_src[e + 2] << 7) + c0);
        const h16x8 v3 = *(const h16x8*)(hb + ((size_t)csr_src[e + 3] << 7) + c0);
        const h16x8 v4 = *(const h16x8*)(hb + ((size_t)csr_src[e + 4] << 7) + c0);
        const h16x8 v5 = *(const h16x8*)(hb + ((size_t)csr_src[e + 5] << 7) + c0);
        const h16x8 v6 = *(const h16x8*)(hb + ((size_t)csr_src[e + 6] << 7) + c0);
        const h16x8 v7 = *(const h16x8*)(hb + ((size_t)csr_src[e + 7] << 7) + c0);
        // fp16 pairwise tree (3 deep, values O(1): err ~1e-2 abs per group)
        h16x8 t0 = v0 + v1, t1 = v2 + v3, t2 = v4 + v5, t3 = v6 + v7;
        h16x8 u0 = t0 + t1, u1 = t2 + t3;
        addh8(a0, a1, u0 + u1);
      }
      if (e + 3 < e1) {
        const h16x8 v0 = *(const h16x8*)(hb + ((size_t)csr_src[e + 0] << 7) + c0);
        const h16x8 v1 = *(const h16x8*)(hb + ((size_t)csr_src[e + 1] << 7) + c0);
        const h16x8 v2 = *(const h16x8*)(hb + ((size_t)csr_src[e + 2] << 7) + c0);
        const h16x8 v3 = *(const h16x8*)(hb + ((size_t)csr_src[e + 3] << 7) + c0);
        h16x8 t0 = v0 + v1, t1 = v2 + v3;
        addh8(a0, a1, t0 + t1);
        e += 4;
      }
      if (e + 1 < e1) {
        const h16x8 v0 = *(const h16x8*)(hb + ((size_t)csr_src[e + 0] << 7) + c0);
        const h16x8 v1 = *(const h16x8*)(hb + ((size_t)csr_src[e + 1] << 7) + c0);
        addh8(a0, a1, v0 + v1);
        e += 2;
      }
      if (e < e1)
        addh8(a0, a1, *(const h16x8*)(hb + ((size_t)csr_src[e] << 7) + c0));
    }
    *(float4*)&zs[lr][c0 + 0] = a0;
    *(float4*)&zs[lr][c0 + 4] = a1;
  }
  __syncthreads();

  // ---- phase 2: MFMA M=32 ----
  const int wv = tid >> 6;
  const int stripe = wv >> 2, half = (wv >> 1) & 1, cpair = wv & 1;
  const int lane = tid & 63, q = lane >> 4, m = lane & 15;
  f32x4 acc[2] = {};
  mfma_phase32(tid, wf, zs, acc);

  // ---- epilogue: bias, fp16 z1 store, BN partials (8 slots/col) ----
  float* red_s = (float*)zs;          // 128*9
  float* red_q = red_s + 1152;        // 128*9
  const int sl = stripe * 4 + q;      // 0..7
  #pragma unroll
  for (int j = 0; j < 2; ++j) {
    const int ct = cpair * 2 + j;
    const int col = half * 64 + ct * 16 + m;
    const float bb = bias[col];
    float s = 0.f, qq = 0.f;
    #pragma unroll
    for (int i = 0; i < 4; ++i) {
      int r = m0 + stripe * 16 + q * 4 + i;
      if (r < NN) {
        float o = acc[j][i] + bb;
        zb[((size_t)r << 7) + col] = (_Float16)o;
        s += o; qq += o * o;
      }
    }
    red_s[col * 9 + sl] = s;
    red_q[col * 9 + sl] = qq;
  }
  __syncthreads();
  if (tid < 128) {
    float s = 0.f, qq = 0.f;
    #pragma unroll
    for (int k = 0; k < 8; ++k) {
      s += red_s[tid * 9 + k];
      qq += red_q[tid * 9 + k];
    }
    float* pb = ps + (blockIdx.x & (NBUCK - 1)) * 256;
    atomicAdd(&pb[tid], s);
    atomicAdd(&pb[128 + tid], qq);
  }
}

// ---------------- FUSED2 v2: 32-row tile (grid 1563) --------------------------
__global__ __launch_bounds__(512) void k_fused2(
    const _Float16* __restrict__ zb, const float* __restrict__ ps,
    const float* __restrict__ gamma, const float* __restrict__ beta,
    const __bf16* __restrict__ wf, const float* __restrict__ bias,
    _Float16* __restrict__ hb, const int* __restrict__ batch,
    float* __restrict__ pooled, int layer)
{
  __shared__ float zs[32][132];
  __shared__ float sab[256];
  const int tid = threadIdx.x;
  const int m0 = blockIdx.x * 32;

  // ---- phase 0: BN finalize from bucketed atomic sums (16 KB, L2-resident) ----
  if (tid < 128) {
    float s = 0.f, q = 0.f;
    #pragma unroll
    for (int b = 0; b < NBUCK; ++b) {
      s += ps[b * 256 + tid];
      q += ps[b * 256 + 128 + tid];
    }
    float mean = s * (1.f / NN);
    float var = q * (1.f / NN) - mean * mean;
    float rstd = rsqrtf(var + 1e-5f);
    float a = gamma[tid] * rstd;
    sab[tid] = a;
    sab[128 + tid] = beta[tid] - mean * a;
  }
  __syncthreads();

  // ---- phase 1: coalesced fp16 load + vector affine + relu -> zs ----
  {
    const int lr = tid >> 4;     // 0..31 rows
    const int sub = tid & 15;    // 8 cols
    const int r = m0 + lr;
    const int c0 = sub << 3;
    h16x8 u0 = {};
    if (r < NN) u0 = *(const h16x8*)(zb + ((size_t)r << 7) + c0);
    float4 v0 = make_float4((float)u0[0], (float)u0[1], (float)u0[2], (float)u0[3]);
    float4 v1 = make_float4((float)u0[4], (float)u0[5], (float)u0[6], (float)u0[7]);
    float4 s0 = *(float4*)&sab[c0], s1 = *(float4*)&sab[c0 + 4];
    float4 o0 = *(float4*)&sab[128 + c0], o1 = *(float4*)&sab[128 + c0 + 4];
    float4 y0, y1;
    y0.x = fmaxf(fmaf(s0.x, v0.x, o0.x), 0.f); y0.y = fmaxf(fmaf(s0.y, v0.y, o0.y), 0.f);
    y0.z = fmaxf(fmaf(s0.z, v0.z, o0.z), 0.f); y0.w = fmaxf(fmaf(s0.w, v0.w, o0.w), 0.f);
    y1.x = fmaxf(fmaf(s1.x, v1.x, o1.x), 0.f); y1.y = fmaxf(fmaf(s1.y, v1.y, o1.y), 0.f);
    y1.z = fmaxf(fmaf(s1.z, v1.z, o1.z), 0.f); y1.w = fmaxf(fmaf(s1.w, v1.w, o1.w), 0.f);
    *(float4*)&zs[lr][c0 + 0] = y0;
    *(float4*)&zs[lr][c0 + 4] = y1;
  }
  __syncthreads();

  // ---- phase 2: MFMA M=32 ----
  const int wv = tid >> 6;
  const int stripe = wv >> 2, half = (wv >> 1) & 1, cpair = wv & 1;
  const int lane = tid & 63, q = lane >> 4, m = lane & 15;
  f32x4 acc[2] = {};
  mfma_phase32(tid, wf, zs, acc);

  // ---- epilogue: bias+relu, fp16 h store, pooling ----
  int bg[4];
  #pragma unroll
  for (int i = 0; i < 4; ++i) {
    int r = m0 + stripe * 16 + q * 4 + i;
    bg[i] = (r < NN) ? batch[r] : -1;
  }
  #pragma unroll
  for (int j = 0; j < 2; ++j) {
    const int ct = cpair * 2 + j;
    const int col = half * 64 + ct * 16 + m;
    const float bb = bias[col];
    #pragma unroll
    for (int i = 0; i < 4; ++i) {
      int r = m0 + stripe * 16 + q * 4 + i;
      float v = fmaxf(acc[j][i] + bb, 0.f);
      acc[j][i] = v;
      if (r < NN) hb[((size_t)r << 7) + col] = (_Float16)v;
    }
  }

  int gstart = batch[m0];
  int gend = batch[(m0 + 31 < NN) ? (m0 + 31) : (NN - 1)];
  float* red_s = (float*)zs;          // 128*9
  float* red_m = red_s + 1152;        // 128*9
  const int sl = stripe * 4 + q;      // 0..7
  for (int g = gstart; g <= gend; ++g) {
    __syncthreads();
    #pragma unroll
    for (int j = 0; j < 2; ++j) {
      const int ct = cpair * 2 + j;
      const int col = half * 64 + ct * 16 + m;
      float s = 0.f, mx = 0.f;
      #pragma unroll
      for (int i = 0; i < 4; ++i) {
        if (bg[i] == g) { s += acc[j][i]; mx = fmaxf(mx, acc[j][i]); }
      }
      red_s[col * 9 + sl] = s;
      red_m[col * 9 + sl] = mx;
    }
    __syncthreads();
    if (tid < 128) {
      float s = 0.f, mx = 0.f;
      #pragma unroll
      for (int k = 0; k < 8; ++k) {
        s += red_s[tid * 9 + k];
        mx = fmaxf(mx, red_m[tid * 9 + k]);
      }
      if (s != 0.f) atomicAdd(&pooled[g * 1792 + layer * 128 + tid], s);
      if (mx != 0.f)
        atomicMax((int*)&pooled[g * 1792 + 896 + layer * 128 + tid], __float_as_int(mx));
    }
  }
}

// ---------------- Wl1 prep: transpose + split via LDS tiles ----------------
__global__ __launch_bounds__(256) void k_wl1prep(
    const float* __restrict__ Wl1, __bf16* __restrict__ wh, __bf16* __restrict__ wl) {
  __shared__ float tile[32][33];
  const int k0 = blockIdx.x * 32, n0 = blockIdx.y * 32;
  const int lr = threadIdx.x >> 5, lc = threadIdx.x & 31;
  #pragma unroll
  for (int it = 0; it < 4; ++it) {
    int rr = lr + it * 8;
    tile[rr][lc] = Wl1[(size_t)(k0 + rr) * 1792 + n0 + lc];
  }
  __syncthreads();
  #pragma unroll
  for (int it = 0; it < 4; ++it) {
    int rr = lr + it * 8;
    float v = tile[lc][rr];
    __bf16 h = (__bf16)v;
    wh[(size_t)(n0 + rr) * 1792 + k0 + lc] = h;
    wl[(size_t)(n0 + rr) * 1792 + k0 + lc] = (__bf16)(v - (float)h);
  }
}

// ---------------- MLP1 (MFMA split-bf16, split-K=4): part = pooled @ Wl1 ----------
__global__ __launch_bounds__(256) void k_mlp1a(
    const float* __restrict__ P, const __bf16* __restrict__ wh,
    const __bf16* __restrict__ wl, float* __restrict__ part)
{
  const int tid = threadIdx.x;
  const int n0 = blockIdx.x * 64;
  const int m0 = blockIdx.y * 64;
  const int kc = blockIdx.z;          // 0..3, chunk of 448 k
  const int kbase = kc * 448;
  const int w = tid >> 6, lane = tid & 63, q = lane >> 4, m = lane & 15;
  const int row = m0 + w * 16 + m;    // < 256 always
  f32x4 acc[4] = {};
  const float* rp = P + (size_t)row * 1792;
  #pragma unroll 2
  for (int ks = 0; ks < 14; ++ks) {
    const int k0 = kbase + ks * 32 + q * 8;
    float4 v0 = ld4(rp + k0), v1 = ld4(rp + k0 + 4);
    bf16x8 ah, al;
    split8(v0, v1, ah, al);
    #pragma unroll
    for (int ct = 0; ct < 4; ++ct) {
      const int n = n0 + ct * 16 + m;
      bf16x8 bh = *(const bf16x8*)(wh + (size_t)n * 1792 + k0);
      bf16x8 bl = *(const bf16x8*)(wl + (size_t)n * 1792 + k0);
      acc[ct] = __builtin_amdgcn_mfma_f32_16x16x32_bf16(ah, bh, acc[ct], 0, 0, 0);
      acc[ct] = __builtin_amdgcn_mfma_f32_16x16x32_bf16(ah, bl, acc[ct], 0, 0, 0);
      acc[ct] = __builtin_amdgcn_mfma_f32_16x16x32_bf16(al, bh, acc[ct], 0, 0, 0);
    }
  }
  float* pp = part + (size_t)kc * 458752;
  #pragma unroll
  for (int ct = 0; ct < 4; ++ct) {
    const int n = n0 + ct * 16 + m;
    #pragma unroll
    for (int i = 0; i < 4; ++i) {
      int r = m0 + w * 16 + q * 4 + i;
      pp[(size_t)r * 1792 + n] = acc[ct][i];
    }
  }
}

// ---------------- MLP2 (merged: relu(part-sum + bl1) dot Wl2, per-group) ---------
__global__ void k_mlp2(const float* __restrict__ part, const float* __restrict__ bl1,
                       const float* __restrict__ Wl2, const float* __restrict__ bl2,
                       float* __restrict__ out) {
  __shared__ float red[256];
  int g = blockIdx.x, t = threadIdx.x;
  float p = 0.f;
  for (int k = t; k < 1792; k += 256) {
    size_t idx = (size_t)g * 1792 + k;
    float s = bl1[k];
    #pragma unroll
    for (int kc = 0; kc < 4; ++kc) s += part[(size_t)kc * 458752 + idx];
    p += fmaxf(s, 0.f) * Wl2[k];
  }
  red[t] = p;
  __syncthreads();
  for (int s = 128; s > 0; s >>= 1) {
    if (t < s) red[t] += red[t + s];
    __syncthreads();
  }
  if (t == 0) {
    float l = red[0] + bl2[0];
    out[g] = 1.f / (1.f + expf(-l));
    out[NG + g] = l;
  }
}

// ---------------- launch ----------------
extern "C" void kernel_launch(void* const* d_in, const int* in_sizes, int n_in,
                              void* d_out, int out_size, void* d_ws, size_t ws_size,
                              hipStream_t stream) {
  const float* x     = (const float*)d_in[0];
  const int*   edge  = (const int*)d_in[1];
  const int*   batch = (const int*)d_in[2];
  const float* W1    = (const float*)d_in[3];
  const float* b1    = (const float*)d_in[4];
  const float* gamma = (const float*)d_in[5];
  const float* beta  = (const float*)d_in[6];
  const float* W2    = (const float*)d_in[7];
  const float* b2    = (const float*)d_in[8];
  const float* Wl1   = (const float*)d_in[9];
  const float* bl1   = (const float*)d_in[10];
  const float* Wl2   = (const float*)d_in[11];
  const float* bl2   = (const float*)d_in[12];
  float* out = (float*)d_out;

  int* wsi = (int*)d_ws;
  int* row_ptr = wsi;                 // 50048
  int* gcur    = wsi + 100608;        // 64 (pad to 100864)
  unsigned short* csr16 = (unsigned short*)(wsi + 100864);  // 800000 u16
  float* wsf   = (float*)(wsi + 950912);
  // float-region layout:
  _Float16* zb     = (_Float16*)wsf;            // [50000,128] fp16 z1 (3.2M floats)
  _Float16* hb     = (_Float16*)(wsf + 6400000);// [50000,128] fp16 h (3.2M floats)
  float*    part   = wsf + 9600000;             // [4][256][1792] (MLP head only)
  float*    psums  = wsf + 12800000;            // [7][16][2][128] bucketed BN sums
  float*    pooled = wsf + 13000448;            // [256,1792] -> ends 13459200
  __bf16*   w1f    = (__bf16*)(wsf + 13459200); // 7*32768 bf16 frag-ordered
  __bf16*   w2f    = (__bf16*)(wsf + 13573888); // 7*32768 bf16 -> ends 13688576
  // bins aliases zb region (dead until first fused1; binB completes before layers)
  unsigned int* bins = (unsigned int*)wsf;      // 49*18432 u32 = 3.6 MB << zb size
  // post-layer aliases (zb region dead after last k_fused2):
  __bf16*   wl1h   = (__bf16*)wsf;              // 1792*1792 bf16
  __bf16*   wl1l   = (__bf16*)(wsf + 1605632);  // ends 3,211,264

  // prep: zeros + x->fp16 + frag-ordered W split; binned CSR (binB computes
  // row_ptr internally -> hist/part/bscan/rowptr kernels eliminated, R12)
  k_init<<<25000, 256, 0, stream>>>(x, W1, W2, gcur, pooled, hb, w1f, w2f, psums);
  k_binA<<<256, 256, 0, stream>>>(edge, gcur, bins);
  k_binB<<<49, 512, 0, stream>>>(gcur, bins, csr16, row_ptr);

  for (int i = 0; i < NLAY; ++i) {
    k_fused1<<<NBLK1, 512, 0, stream>>>(hb, row_ptr, csr16, w1f + i * 32768,
                                        b1 + i * 128, zb, psums + i * NBUCK * 256);
    k_fused2<<<NBLK1, 512, 0, stream>>>(zb, psums + i * NBUCK * 256, gamma + i * 128,
                                        beta + i * 128, w2f + i * 32768,
                                        b2 + i * 128, hb, batch, pooled, i);
  }
  // MLP head (zb region reused for Wl1 split)
  k_wl1prep<<<dim3(56, 56), 256, 0, stream>>>(Wl1, wl1h, wl1l);
  k_mlp1a<<<dim3(28, 4, 4), 256, 0, stream>>>(pooled, wl1h, wl1l, part);
  k_mlp2<<<256, 256, 0, stream>>>(part, bl1, Wl2, bl2, out);
}

// Round 20
// 575.575 us; speedup vs baseline: 1.3524x; 1.0073x over previous
//
#include <hip/hip_runtime.h>
#include <cstdint>
#include <cstddef>

#define NN 50000
#define NE 800000
#define NG 256
#define NLAY 7
#define NBLK1 1563 // 32-row tiles (fused1 AND fused2)
#define NBUCK 16   // BN atomic buckets (contention 1563 -> ~98 per address)
#define CAP 18432  // bins capacity per dst-range

typedef float f32x4 __attribute__((ext_vector_type(4)));
typedef __bf16 bf16x8 __attribute__((ext_vector_type(8)));
typedef _Float16 h16x8 __attribute__((ext_vector_type(8)));

__device__ __forceinline__ float4 ld4(const float* p) { return *(const float4*)p; }
__device__ __forceinline__ void addh8(float4& x, float4& y, h16x8 v) {
  x.x += (float)v[0]; x.y += (float)v[1]; x.z += (float)v[2]; x.w += (float)v[3];
  y.x += (float)v[4]; y.y += (float)v[5]; y.z += (float)v[6]; y.w += (float)v[7];
}

// ---------------- init: zeros + hb=fp16(x) + W1/W2 -> MFMA-fragment order --------
// wf layout: pos = ((kc*16 + slot)*64 + lane)*8 + j, slot = (half*4+ct)*2 + hl.
__global__ void k_init(const float* __restrict__ x, const float* __restrict__ W1,
                       const float* __restrict__ W2,
                       int* __restrict__ gcur, float* __restrict__ pooled,
                       _Float16* __restrict__ hb,
                       __bf16* __restrict__ w1f, __bf16* __restrict__ w2f,
                       float* __restrict__ psums) {
  int i = blockIdx.x * 256 + threadIdx.x;  // grid 25000 -> 6.4M
  if (i < 49) gcur[i] = i * CAP;
  if (i < NLAY * NBUCK * 256) psums[i] = 0.f;  // per-layer bucketed BN accumulators
  if (i < NG * 1792) pooled[i] = 0.f;
  if (i < NN * 128) hb[i] = (_Float16)x[i];
  if (i < NLAY * 32768) {
    int l = i >> 15, pos = i & 32767;
    int j = pos & 7, ln = (pos >> 3) & 63, slot = (pos >> 9) & 15, kc = pos >> 13;
    int hl = slot & 1, ctp = (slot >> 1) & 3, hfp = slot >> 3;
    int n = hfp * 64 + ctp * 16 + (ln & 15);
    int k = kc * 32 + ((ln >> 4) << 3) + j;
    float a = W1[l * 16384 + k * 128 + n];
    float b = W2[l * 16384 + k * 128 + n];
    __bf16 ah = (__bf16)a, bh = (__bf16)b;
    w1f[i] = hl ? (__bf16)(a - (float)ah) : ah;
    w2f[i] = hl ? (__bf16)(b - (float)bh) : bh;
  }
}

// ---------------- binned CSR build (A: scatter to 1024-row bins) ----------------
__global__ __launch_bounds__(256) void k_binA(const int* __restrict__ edge,
                                              int* __restrict__ gcur,
                                              unsigned int* __restrict__ bins) {
  __shared__ int lh[49], lbase[49], lt[49];
  const int tid = threadIdx.x;
  const int e0 = blockIdx.x * 3125, e1 = e0 + 3125;
  if (tid < 49) { lh[tid] = 0; lt[tid] = 0; }
  __syncthreads();
  for (int e = e0 + tid; e < e1; e += 256)
    atomicAdd(&lh[edge[NE + e] >> 10], 1);
  __syncthreads();
  if (tid < 49) lbase[tid] = atomicAdd(&gcur[tid], lh[tid]);
  __syncthreads();
  for (int e = e0 + tid; e < e1; e += 256) {
    int dst = edge[NE + e], src = edge[e];
    int r = dst >> 10;
    int t = atomicAdd(&lt[r], 1);
    bins[lbase[r] + t] = ((unsigned)dst << 16) | (unsigned)src;
  }
}

// ---------------- binB v2: per-bin histogram + in-LDS scan -> row_ptr + csr16 ----
__global__ __launch_bounds__(512) void k_binB(const int* __restrict__ gcur,
                                              const unsigned int* __restrict__ bins,
                                              unsigned short* __restrict__ csr16,
                                              int* __restrict__ row_ptr) {
  __shared__ int lhist[1024];
  __shared__ int lcur[1024];
  __shared__ int sm[512];
  __shared__ unsigned short lcsr[24576];  // 48 KB (LDS total ~58 KB)
  const int blk = blockIdx.x, tid = threadIdx.x;
  const int base = blk << 10;
  const int tot = gcur[blk] - blk * CAP;
  int seg0 = 0;
  for (int k = 0; k < blk; ++k) seg0 += gcur[k] - k * CAP;  // <=48 L1-hot loads
  for (int i = tid; i < 1024; i += 512) lhist[i] = 0;
  __syncthreads();
  // pass 1: per-row histogram
  for (int t = tid; t < tot; t += 512)
    atomicAdd(&lhist[(int)(bins[blk * CAP + t] >> 16) - base], 1);
  __syncthreads();
  // exclusive scan over 1024 rows: 2 elems/thread + 512-wide Hillis-Steele
  int a = lhist[2 * tid], b = lhist[2 * tid + 1];
  int pair = a + b;
  sm[tid] = pair;
  __syncthreads();
  int val = pair;
  for (int off = 1; off < 512; off <<= 1) {
    int o = (tid >= off) ? sm[tid - off] : 0;
    __syncthreads();
    val += o;
    sm[tid] = val;
    __syncthreads();
  }
  int e0 = val - pair;         // exclusive offset of row 2*tid
  int e1 = e0 + a;             // exclusive offset of row 2*tid+1
  lcur[2 * tid] = e0;
  lcur[2 * tid + 1] = e1;
  if (base + 2 * tid < NN)     row_ptr[base + 2 * tid] = seg0 + e0;
  if (base + 2 * tid + 1 < NN) row_ptr[base + 2 * tid + 1] = seg0 + e1;
  if (blk == 48 && tid == 0)   row_ptr[NN] = seg0 + tot;  // = NE
  __syncthreads();
  // pass 2: scatter into compacted per-row segments
  for (int t = tid; t < tot; t += 512) {
    unsigned int p = bins[blk * CAP + t];
    int dst = (int)(p >> 16), src = (int)(p & 0xffffu);
    int pos = atomicAdd(&lcur[dst - base], 1);
    lcsr[pos] = (unsigned short)src;
  }
  __syncthreads();
  for (int i = tid; i < tot; i += 512) csr16[seg0 + i] = lcsr[i];
}

// ---------------- split fp32x8 -> bf16 hi/lo fragments ----------------
__device__ __forceinline__ void split8(const float4 v0, const float4 v1,
                                       bf16x8& hi, bf16x8& lo) {
  float f[8] = {v0.x, v0.y, v0.z, v0.w, v1.x, v1.y, v1.z, v1.w};
  #pragma unroll
  for (int j = 0; j < 8; ++j) {
    __bf16 h = (__bf16)f[j];
    hi[j] = h;
    lo[j] = (__bf16)(f[j] - (float)h);
  }
}

// ---------------- MFMA phase (M=32, 8 waves, acc[2]) for fused1 ----------------
__device__ __forceinline__ void mfma_phase32(
    int tid, const __bf16* __restrict__ wf, float (*zs)[132], f32x4 acc[2])
{
  const int wv = tid >> 6;
  const int stripe = wv >> 2, half = (wv >> 1) & 1, cpair = wv & 1;
  const int lane = tid & 63, q = lane >> 4, m = lane & 15;
  #pragma unroll
  for (int kc = 0; kc < 4; ++kc) {
    const int k0 = kc * 32 + q * 8;
    float4 v0 = *(const float4*)&zs[stripe * 16 + m][k0];
    float4 v1 = *(const float4*)&zs[stripe * 16 + m][k0 + 4];
    bf16x8 ah, al;
    split8(v0, v1, ah, al);
    #pragma unroll
    for (int j = 0; j < 2; ++j) {
      const int ct = cpair * 2 + j;
      const int sbase = (half * 4 + ct) * 2;
      const __bf16* bp = wf + (((size_t)(kc * 16 + sbase) * 64 + lane) << 3);
      bf16x8 bh = *(const bf16x8*)bp;
      bf16x8 bl = *(const bf16x8*)(bp + 512);  // slot+1 = +64 lanes * 8
      acc[j] = __builtin_amdgcn_mfma_f32_16x16x32_bf16(ah, bh, acc[j], 0, 0, 0);
      acc[j] = __builtin_amdgcn_mfma_f32_16x16x32_bf16(ah, bl, acc[j], 0, 0, 0);
      acc[j] = __builtin_amdgcn_mfma_f32_16x16x32_bf16(al, bh, acc[j], 0, 0, 0);
    }
  }
  __syncthreads();  // zs dead after; callers reuse as scratch
}

// ---------------- FUSED1 v4: 32-row tile, 8-edge ILP + 4/2/1 tail cascade -------
// Bucketed BN atomics (R8 lesson: single-buffer atomics = +18us RMW serialization).
__global__ __launch_bounds__(512, 8) void k_fused1(
    const _Float16* __restrict__ hb, const int* __restrict__ row_ptr,
    const unsigned short* __restrict__ csr_src, const __bf16* __restrict__ wf,
    const float* __restrict__ bias, _Float16* __restrict__ zb,
    float* __restrict__ ps)   // ps = psums + layer*NBUCK*256; bucket b at ps+b*256
{
  __shared__ float zs[32][132];
  const int tid = threadIdx.x;
  const int m0 = blockIdx.x * 32;

  // ---- phase 1: gather agg = h[r] + sum h[src] ----
  {
    const int lr = tid >> 4;     // 0..31 rows
    const int sub = tid & 15;    // 8 cols each
    const int r = m0 + lr;
    const int c0 = sub << 3;
    float4 a0 = make_float4(0.f, 0.f, 0.f, 0.f), a1 = a0;
    if (r < NN) {
      addh8(a0, a1, *(const h16x8*)(hb + ((size_t)r << 7) + c0));
      int e = row_ptr[r], e1 = row_ptr[r + 1];
      for (; e + 7 < e1; e += 8) {
        const h16x8 v0 = *(const h16x8*)(hb + ((size_t)csr_src[e + 0] << 7) + c0);
        const h16x8 v1 = *(const h16x8*)(hb + ((size_t)csr_src[e + 1] << 7) + c0);
        const h16x8 v2 = *(const h16x8*)(hb + ((size_t)csr_src[e + 2] << 7) + c0);
        const h16x8 v3 = *(const h16x8*)(hb + ((size_t)csr_src[e + 3] << 7) + c0);
        const h16x8 v4 = *(const h16x8*)(hb + ((size_t)csr_src[e + 4] << 7) + c0);
        const h16x8 v5 = *(const h16x8*)(hb + ((size_t)csr_src[e + 5] << 7) + c0);
        const h16x8 v6 = *(const h16x8*)(hb + ((size_t)csr_src[e + 6] << 7) + c0);
        const h16x8 v7 = *(const h16x8*)(hb + ((size_t)csr_src[e + 7] << 7) + c0);
        // fp16 pairwise tree (3 deep, values O(1): err ~1e-2 abs per group)
        h16x8 t0 = v0 + v1, t1 = v2 + v3, t2 = v4 + v5, t3 = v6 + v7;
        h16x8 u0 = t0 + t1, u1 = t2 + t3;
        addh8(a0, a1, u0 + u1);
      }
      if (e + 3 < e1) {
        const h16x8 v0 = *(const h16x8*)(hb + ((size_t)csr_src[e + 0] << 7) + c0);
        const h16x8 v1 = *(const h16x8*)(hb + ((size_t)csr_src[e + 1] << 7) + c0);
        const h16x8 v2 = *(const h16x8*)(hb + ((size_t)csr_src[e + 2] << 7) + c0);
        const h16x8 v3 = *(const h16x8*)(hb + ((size_t)csr_src[e + 3] << 7) + c0);
        h16x8 t0 = v0 + v1, t1 = v2 + v3;
        addh8(a0, a1, t0 + t1);
        e += 4;
      }
      if (e + 1 < e1) {
        const h16x8 v0 = *(const h16x8*)(hb + ((size_t)csr_src[e + 0] << 7) + c0);
        const h16x8 v1 = *(const h16x8*)(hb + ((size_t)csr_src[e + 1] << 7) + c0);
        addh8(a0, a1, v0 + v1);
        e += 2;
      }
      if (e < e1)
        addh8(a0, a1, *(const h16x8*)(hb + ((size_t)csr_src[e] << 7) + c0));
    }
    *(float4*)&zs[lr][c0 + 0] = a0;
    *(float4*)&zs[lr][c0 + 4] = a1;
  }
  __syncthreads();

  // ---- phase 2: MFMA M=32 ----
  const int wv = tid >> 6;
  const int stripe = wv >> 2, half = (wv >> 1) & 1, cpair = wv & 1;
  const int lane = tid & 63, q = lane >> 4, m = lane & 15;
  f32x4 acc[2] = {};
  mfma_phase32(tid, wf, zs, acc);

  // ---- epilogue: bias, fp16 z1 store, BN partials (8 slots/col) ----
  float* red_s = (float*)zs;          // 128*9
  float* red_q = red_s + 1152;        // 128*9
  const int sl = stripe * 4 + q;      // 0..7
  #pragma unroll
  for (int j = 0; j < 2; ++j) {
    const int ct = cpair * 2 + j;
    const int col = half * 64 + ct * 16 + m;
    const float bb = bias[col];
    float s = 0.f, qq = 0.f;
    #pragma unroll
    for (int i = 0; i < 4; ++i) {
      int r = m0 + stripe * 16 + q * 4 + i;
      if (r < NN) {
        float o = acc[j][i] + bb;
        zb[((size_t)r << 7) + col] = (_Float16)o;
        s += o; qq += o * o;
      }
    }
    red_s[col * 9 + sl] = s;
    red_q[col * 9 + sl] = qq;
  }
  __syncthreads();
  if (tid < 128) {
    float s = 0.f, qq = 0.f;
    #pragma unroll
    for (int k = 0; k < 8; ++k) {
      s += red_s[tid * 9 + k];
      qq += red_q[tid * 9 + k];
    }
    float* pb = ps + (blockIdx.x & (NBUCK - 1)) * 256;
    atomicAdd(&pb[tid], s);
    atomicAdd(&pb[128 + tid], qq);
  }
}

// ---------------- FUSED2 v3: 32-row tile + load-issue pipelining (T14) ---------
// R13 theory: fused2's 35us >> its ~6us traffic/compute floor; serial phase
// latency dominates (BN reads -> barrier -> zb load -> barrier -> first wf load).
// v3 issues the independent load streams (zb row, kc=0 wf fragments, batch ids)
// BEFORE the BN-finalize phase so they fly under it. No numeric change.
__global__ __launch_bounds__(512) void k_fused2(
    const _Float16* __restrict__ zb, const float* __restrict__ ps,
    const float* __restrict__ gamma, const float* __restrict__ beta,
    const __bf16* __restrict__ wf, const float* __restrict__ bias,
    _Float16* __restrict__ hb, const int* __restrict__ batch,
    float* __restrict__ pooled, int layer)
{
  __shared__ float zs[32][132];
  __shared__ float sab[256];
  const int tid = threadIdx.x;
  const int m0 = blockIdx.x * 32;
  const int wv = tid >> 6;
  const int stripe = wv >> 2, half = (wv >> 1) & 1, cpair = wv & 1;
  const int lane = tid & 63, q = lane >> 4, m = lane & 15;

  // ---- issue-early: zb row, kc=0 wf fragments, batch group ids ----
  const int lr = tid >> 4;     // 0..31 rows
  const int sub = tid & 15;    // 8 cols
  const int r1 = m0 + lr;
  const int c0 = sub << 3;
  h16x8 u0 = {};
  if (r1 < NN) u0 = *(const h16x8*)(zb + ((size_t)r1 << 7) + c0);
  bf16x8 pbh[2], pbl[2];       // kc=0 B fragments (16 VGPRs)
  #pragma unroll
  for (int j = 0; j < 2; ++j) {
    const int ct = cpair * 2 + j;
    const int sbase = (half * 4 + ct) * 2;
    const __bf16* bp = wf + (((size_t)sbase * 64 + lane) << 3);
    pbh[j] = *(const bf16x8*)bp;
    pbl[j] = *(const bf16x8*)(bp + 512);
  }
  int bg[4];
  #pragma unroll
  for (int i = 0; i < 4; ++i) {
    int rr = m0 + stripe * 16 + q * 4 + i;
    bg[i] = (rr < NN) ? batch[rr] : -1;
  }

  // ---- BN finalize (executes under the in-flight loads above) ----
  if (tid < 128) {
    float s = 0.f, qv = 0.f;
    #pragma unroll
    for (int b = 0; b < NBUCK; ++b) {
      s += ps[b * 256 + tid];
      qv += ps[b * 256 + 128 + tid];
    }
    float mean = s * (1.f / NN);
    float var = qv * (1.f / NN) - mean * mean;
    float rstd = rsqrtf(var + 1e-5f);
    float a = gamma[tid] * rstd;
    sab[tid] = a;
    sab[128 + tid] = beta[tid] - mean * a;
  }
  __syncthreads();

  // ---- affine + relu -> zs (uses preloaded u0) ----
  {
    float4 v0 = make_float4((float)u0[0], (float)u0[1], (float)u0[2], (float)u0[3]);
    float4 v1 = make_float4((float)u0[4], (float)u0[5], (float)u0[6], (float)u0[7]);
    float4 s0 = *(float4*)&sab[c0], s1 = *(float4*)&sab[c0 + 4];
    float4 o0 = *(float4*)&sab[128 + c0], o1 = *(float4*)&sab[128 + c0 + 4];
    float4 y0, y1;
    y0.x = fmaxf(fmaf(s0.x, v0.x, o0.x), 0.f); y0.y = fmaxf(fmaf(s0.y, v0.y, o0.y), 0.f);
    y0.z = fmaxf(fmaf(s0.z, v0.z, o0.z), 0.f); y0.w = fmaxf(fmaf(s0.w, v0.w, o0.w), 0.f);
    y1.x = fmaxf(fmaf(s1.x, v1.x, o1.x), 0.f); y1.y = fmaxf(fmaf(s1.y, v1.y, o1.y), 0.f);
    y1.z = fmaxf(fmaf(s1.z, v1.z, o1.z), 0.f); y1.w = fmaxf(fmaf(s1.w, v1.w, o1.w), 0.f);
    *(float4*)&zs[lr][c0 + 0] = y0;
    *(float4*)&zs[lr][c0 + 4] = y1;
  }
  __syncthreads();

  // ---- MFMA M=32: kc=0 from preloaded fragments, kc=1..3 inline ----
  f32x4 acc[2] = {};
  {
    const int k0 = q * 8;
    float4 v0 = *(const float4*)&zs[stripe * 16 + m][k0];
    float4 v1 = *(const float4*)&zs[stripe * 16 + m][k0 + 4];
    bf16x8 ah, al;
    split8(v0, v1, ah, al);
    #pragma unroll
    for (int j = 0; j < 2; ++j) {
      acc[j] = __builtin_amdgcn_mfma_f32_16x16x32_bf16(ah, pbh[j], acc[j], 0, 0, 0);
      acc[j] = __builtin_amdgcn_mfma_f32_16x16x32_bf16(ah, pbl[j], acc[j], 0, 0, 0);
      acc[j] = __builtin_amdgcn_mfma_f32_16x16x32_bf16(al, pbh[j], acc[j], 0, 0, 0);
    }
  }
  #pragma unroll
  for (int kc = 1; kc < 4; ++kc) {
    const int k0 = kc * 32 + q * 8;
    float4 v0 = *(const float4*)&zs[stripe * 16 + m][k0];
    float4 v1 = *(const float4*)&zs[stripe * 16 + m][k0 + 4];
    bf16x8 ah, al;
    split8(v0, v1, ah, al);
    #pragma unroll
    for (int j = 0; j < 2; ++j) {
      const int ct = cpair * 2 + j;
      const int sbase = (half * 4 + ct) * 2;
      const __bf16* bp = wf + (((size_t)(kc * 16 + sbase) * 64 + lane) << 3);
      bf16x8 bh = *(const bf16x8*)bp;
      bf16x8 bl = *(const bf16x8*)(bp + 512);
      acc[j] = __builtin_amdgcn_mfma_f32_16x16x32_bf16(ah, bh, acc[j], 0, 0, 0);
      acc[j] = __builtin_amdgcn_mfma_f32_16x16x32_bf16(ah, bl, acc[j], 0, 0, 0);
      acc[j] = __builtin_amdgcn_mfma_f32_16x16x32_bf16(al, bh, acc[j], 0, 0, 0);
    }
  }
  __syncthreads();  // zs dead; reuse as reduction scratch

  // ---- epilogue: bias+relu, fp16 h store, pooling (bg preloaded) ----
  #pragma unroll
  for (int j = 0; j < 2; ++j) {
    const int ct = cpair * 2 + j;
    const int col = half * 64 + ct * 16 + m;
    const float bb = bias[col];
    #pragma unroll
    for (int i = 0; i < 4; ++i) {
      int r = m0 + stripe * 16 + q * 4 + i;
      float v = fmaxf(acc[j][i] + bb, 0.f);
      acc[j][i] = v;
      if (r < NN) hb[((size_t)r << 7) + col] = (_Float16)v;
    }
  }

  int gstart = batch[m0];
  int gend = batch[(m0 + 31 < NN) ? (m0 + 31) : (NN - 1)];
  float* red_s = (float*)zs;          // 128*9
  float* red_m = red_s + 1152;        // 128*9
  const int sl = stripe * 4 + q;      // 0..7
  for (int g = gstart; g <= gend; ++g) {
    __syncthreads();
    #pragma unroll
    for (int j = 0; j < 2; ++j) {
      const int ct = cpair * 2 + j;
      const int col = half * 64 + ct * 16 + m;
      float s = 0.f, mx = 0.f;
      #pragma unroll
      for (int i = 0; i < 4; ++i) {
        if (bg[i] == g) { s += acc[j][i]; mx = fmaxf(mx, acc[j][i]); }
      }
      red_s[col * 9 + sl] = s;
      red_m[col * 9 + sl] = mx;
    }
    __syncthreads();
    if (tid < 128) {
      float s = 0.f, mx = 0.f;
      #pragma unroll
      for (int k = 0; k < 8; ++k) {
        s += red_s[tid * 9 + k];
        mx = fmaxf(mx, red_m[tid * 9 + k]);
      }
      if (s != 0.f) atomicAdd(&pooled[g * 1792 + layer * 128 + tid], s);
      if (mx != 0.f)
        atomicMax((int*)&pooled[g * 1792 + 896 + layer * 128 + tid], __float_as_int(mx));
    }
  }
}

// ---------------- Wl1 prep: transpose + split via LDS tiles ----------------
__global__ __launch_bounds__(256) void k_wl1prep(
    const float* __restrict__ Wl1, __bf16* __restrict__ wh, __bf16* __restrict__ wl) {
  __shared__ float tile[32][33];
  const int k0 = blockIdx.x * 32, n0 = blockIdx.y * 32;
  const int lr = threadIdx.x >> 5, lc = threadIdx.x & 31;
  #pragma unroll
  for (int it = 0; it < 4; ++it) {
    int rr = lr + it * 8;
    tile[rr][lc] = Wl1[(size_t)(k0 + rr) * 1792 + n0 + lc];
  }
  __syncthreads();
  #pragma unroll
  for (int it = 0; it < 4; ++it) {
    int rr = lr + it * 8;
    float v = tile[lc][rr];
    __bf16 h = (__bf16)v;
    wh[(size_t)(n0 + rr) * 1792 + k0 + lc] = h;
    wl[(size_t)(n0 + rr) * 1792 + k0 + lc] = (__bf16)(v - (float)h);
  }
}

// ---------------- MLP1 (MFMA split-bf16, split-K=4): part = pooled @ Wl1 ----------
__global__ __launch_bounds__(256) void k_mlp1a(
    const float* __restrict__ P, const __bf16* __restrict__ wh,
    const __bf16* __restrict__ wl, float* __restrict__ part)
{
  const int tid = threadIdx.x;
  const int n0 = blockIdx.x * 64;
  const int m0 = blockIdx.y * 64;
  const int kc = blockIdx.z;          // 0..3, chunk of 448 k
  const int kbase = kc * 448;
  const int w = tid >> 6, lane = tid & 63, q = lane >> 4, m = lane & 15;
  const int row = m0 + w * 16 + m;    // < 256 always
  f32x4 acc[4] = {};
  const float* rp = P + (size_t)row * 1792;
  #pragma unroll 2
  for (int ks = 0; ks < 14; ++ks) {
    const int k0 = kbase + ks * 32 + q * 8;
    float4 v0 = ld4(rp + k0), v1 = ld4(rp + k0 + 4);
    bf16x8 ah, al;
    split8(v0, v1, ah, al);
    #pragma unroll
    for (int ct = 0; ct < 4; ++ct) {
      const int n = n0 + ct * 16 + m;
      bf16x8 bh = *(const bf16x8*)(wh + (size_t)n * 1792 + k0);
      bf16x8 bl = *(const bf16x8*)(wl + (size_t)n * 1792 + k0);
      acc[ct] = __builtin_amdgcn_mfma_f32_16x16x32_bf16(ah, bh, acc[ct], 0, 0, 0);
      acc[ct] = __builtin_amdgcn_mfma_f32_16x16x32_bf16(ah, bl, acc[ct], 0, 0, 0);
      acc[ct] = __builtin_amdgcn_mfma_f32_16x16x32_bf16(al, bh, acc[ct], 0, 0, 0);
    }
  }
  float* pp = part + (size_t)kc * 458752;
  #pragma unroll
  for (int ct = 0; ct < 4; ++ct) {
    const int n = n0 + ct * 16 + m;
    #pragma unroll
    for (int i = 0; i < 4; ++i) {
      int r = m0 + w * 16 + q * 4 + i;
      pp[(size_t)r * 1792 + n] = acc[ct][i];
    }
  }
}

// ---------------- MLP2 (merged: relu(part-sum + bl1) dot Wl2, per-group) ---------
__global__ void k_mlp2(const float* __restrict__ part, const float* __restrict__ bl1,
                       const float* __restrict__ Wl2, const float* __restrict__ bl2,
                       float* __restrict__ out) {
  __shared__ float red[256];
  int g = blockIdx.x, t = threadIdx.x;
  float p = 0.f;
  for (int k = t; k < 1792; k += 256) {
    size_t idx = (size_t)g * 1792 + k;
    float s = bl1[k];
    #pragma unroll
    for (int kc = 0; kc < 4; ++kc) s += part[(size_t)kc * 458752 + idx];
    p += fmaxf(s, 0.f) * Wl2[k];
  }
  red[t] = p;
  __syncthreads();
  for (int s = 128; s > 0; s >>= 1) {
    if (t < s) red[t] += red[t + s];
    __syncthreads();
  }
  if (t == 0) {
    float l = red[0] + bl2[0];
    out[g] = 1.f / (1.f + expf(-l));
    out[NG + g] = l;
  }
}

// ---------------- launch ----------------
extern "C" void kernel_launch(void* const* d_in, const int* in_sizes, int n_in,
                              void* d_out, int out_size, void* d_ws, size_t ws_size,
                              hipStream_t stream) {
  const float* x     = (const float*)d_in[0];
  const int*   edge  = (const int*)d_in[1];
  const int*   batch = (const int*)d_in[2];
  const float* W1    = (const float*)d_in[3];
  const float* b1    = (const float*)d_in[4];
  const float* gamma = (const float*)d_in[5];
  const float* beta  = (const float*)d_in[6];
  const float* W2    = (const float*)d_in[7];
  const float* b2    = (const float*)d_in[8];
  const float* Wl1   = (const float*)d_in[9];
  const float* bl1   = (const float*)d_in[10];
  const float* Wl2   = (const float*)d_in[11];
  const float* bl2   = (const float*)d_in[12];
  float* out = (float*)d_out;

  int* wsi = (int*)d_ws;
  int* row_ptr = wsi;                 // 50048
  int* gcur    = wsi + 100608;        // 64 (pad to 100864)
  unsigned short* csr16 = (unsigned short*)(wsi + 100864);  // 800000 u16
  float* wsf   = (float*)(wsi + 950912);
  // float-region layout:
  _Float16* zb     = (_Float16*)wsf;            // [50000,128] fp16 z1 (3.2M floats)
  _Float16* hb     = (_Float16*)(wsf + 6400000);// [50000,128] fp16 h (3.2M floats)
  float*    part   = wsf + 9600000;             // [4][256][1792] (MLP head only)
  float*    psums  = wsf + 12800000;            // [7][16][2][128] bucketed BN sums
  float*    pooled = wsf + 13000448;            // [256,1792] -> ends 13459200
  __bf16*   w1f    = (__bf16*)(wsf + 13459200); // 7*32768 bf16 frag-ordered
  __bf16*   w2f    = (__bf16*)(wsf + 13573888); // 7*32768 bf16 -> ends 13688576
  // bins aliases zb region (dead until first fused1; binB completes before layers)
  unsigned int* bins = (unsigned int*)wsf;      // 49*18432 u32 = 3.6 MB << zb size
  // post-layer aliases (zb region dead after last k_fused2):
  __bf16*   wl1h   = (__bf16*)wsf;              // 1792*1792 bf16
  __bf16*   wl1l   = (__bf16*)(wsf + 1605632);  // ends 3,211,264

  // prep: zeros + x->fp16 + frag-ordered W split; binned CSR (binB computes
  // row_ptr internally -> hist/part/bscan/rowptr kernels eliminated, R12)
  k_init<<<25000, 256, 0, stream>>>(x, W1, W2, gcur, pooled, hb, w1f, w2f, psums);
  k_binA<<<256, 256, 0, stream>>>(edge, gcur, bins);
  k_binB<<<49, 512, 0, stream>>>(gcur, bins, csr16, row_ptr);

  for (int i = 0; i < NLAY; ++i) {
    k_fused1<<<NBLK1, 512, 0, stream>>>(hb, row_ptr, csr16, w1f + i * 32768,
                                        b1 + i * 128, zb, psums + i * NBUCK * 256);
    k_fused2<<<NBLK1, 512, 0, stream>>>(zb, psums + i * NBUCK * 256, gamma + i * 128,
                                        beta + i * 128, w2f + i * 32768,
                                        b2 + i * 128, hb, batch, pooled, i);
  }
  // MLP head (zb region reused for Wl1 split)
  k_wl1prep<<<dim3(56, 56), 256, 0, stream>>>(Wl1, wl1h, wl1l);
  k_mlp1a<<<dim3(28, 4, 4), 256, 0, stream>>>(pooled, wl1h, wl1l, part);
  k_mlp2<<<256, 256, 0, stream>>>(part, bl1, Wl2, bl2, out);
}